// Round 1
// baseline (79130.194 us; speedup 1.0000x reference)
//
#include <hip/hip_runtime.h>
#include <stdint.h>

#define NPTS 1024
#define NDRAWS 20
#define NSTEPS 10
#define NG 100
#define PARTITIONABLE 1

typedef unsigned int u32;

// ---------------- threefry2x32 (JAX-compatible, 20 rounds) ----------------
__host__ __device__ static inline void tf2x32(u32 k0, u32 k1, u32 x0, u32 x1, u32* o0, u32* o1){
  u32 ks2 = k0 ^ k1 ^ 0x1BD11BDAu;
  x0 += k0; x1 += k1;
#define TFR(r) { x0 += x1; x1 = (x1 << r) | (x1 >> (32 - r)); x1 ^= x0; }
  TFR(13) TFR(15) TFR(26) TFR(6)
  x0 += k1; x1 += ks2 + 1u;
  TFR(17) TFR(29) TFR(16) TFR(24)
  x0 += ks2; x1 += k0 + 2u;
  TFR(13) TFR(15) TFR(26) TFR(6)
  x0 += k0; x1 += k1 + 3u;
  TFR(17) TFR(29) TFR(16) TFR(24)
  x0 += k1; x1 += ks2 + 4u;
  TFR(13) TFR(15) TFR(26) TFR(6)
  x0 += ks2; x1 += k0 + 5u;
#undef TFR
  *o0 = x0; *o1 = x1;
}

__device__ static inline u32 rand32(u32 ka, u32 kb, u32 i, u32 total){
  u32 a, b;
#if PARTITIONABLE
  (void)total;
  tf2x32(ka, kb, 0u, i, &a, &b);
  return a ^ b;
#else
  u32 h = total >> 1;
  if (i < h){ tf2x32(ka, kb, i, i + h, &a, &b); return a; }
  else      { tf2x32(ka, kb, i - h, i, &a, &b); return b; }
#endif
}

__device__ static inline float u01f(u32 bits){
  return __uint_as_float(0x3F800000u | (bits >> 9)) - 1.0f;
}

// XLA ErfInv32 (Giles) polynomial — matches jax.lax.erf_inv for f32
__device__ static inline float erfinv32(float x){
  float w = -log1pf(-x * x);
  float p;
  if (w < 5.0f){
    w -= 2.5f;
    p = 2.81022636e-08f;
    p = fmaf(p, w, 3.43273939e-07f);
    p = fmaf(p, w, -3.5233877e-06f);
    p = fmaf(p, w, -4.39150654e-06f);
    p = fmaf(p, w, 0.00021858087f);
    p = fmaf(p, w, -0.00125372503f);
    p = fmaf(p, w, -0.00417768164f);
    p = fmaf(p, w, 0.246640727f);
    p = fmaf(p, w, 1.50140941f);
  } else {
    w = sqrtf(w) - 3.0f;
    p = -0.000200214257f;
    p = fmaf(p, w, 0.000100950558f);
    p = fmaf(p, w, 0.00134934322f);
    p = fmaf(p, w, -0.00367342844f);
    p = fmaf(p, w, 0.00573950773f);
    p = fmaf(p, w, -0.0076224613f);
    p = fmaf(p, w, 0.00943887047f);
    p = fmaf(p, w, 1.00167406f);
    p = fmaf(p, w, 2.83297682f);
  }
  return p * x;
}

__device__ static inline float normal_from_bits(u32 bits){
  const float LO = -0.99999994f;   // nextafter(-1,0) in f32
  float u = u01f(bits);
  float v = u * 2.0f + LO;         // (maxval-minval)==2.0f exactly in f32
  v = fmaxf(LO, v);
  return 1.4142135623730951f * erfinv32(v);
}

__device__ inline float  tsqrt(float x){ return sqrtf(x); }
__device__ inline double tsqrt(double x){ return sqrt(x); }
__device__ inline float  tmax(float a, float b){ return fmaxf(a, b); }
__device__ inline double tmax(double a, double b){ return fmax(a, b); }

__device__ inline void tri_decode(int p, int& ti, int& tj){
  int t = (int)((sqrtf(8.0f * (float)p + 1.0f) - 1.0f) * 0.5f);
  while ((t + 1) * (t + 2) / 2 <= p) ++t;
  while (t * (t + 1) / 2 > p) --t;
  ti = t; tj = p - t * (t + 1) / 2;
}

// ---------------- setup kernels ----------------
__global__ __launch_bounds__(256) void k_prep(const float* X, const int* Y, float* x2, float* kappa){
  int n = blockIdx.x * 256 + threadIdx.x;
  if (n >= NPTS) return;
  float s = 0.f;
  for (int d = 0; d < 64; ++d){ float v = X[n * 64 + d]; s += v * v; }
  x2[n] = s;
  kappa[n] = (float)Y[n] - 0.5f;
}

__global__ void k_computeK(const float* X, const float* x2, const float* osp, const float* lsp,
                           float* K, double* Ld){
  int j = blockIdx.x * 16 + threadIdx.x;
  int i = blockIdx.y * 16 + threadIdx.y;
  float os = osp[0], ls = lsp[0];
  float dot = 0.f;
  for (int d = 0; d < 64; ++d) dot += X[i * 64 + d] * X[j * 64 + d];
  float d2 = x2[i] + x2[j] - 2.0f * dot;
  d2 = fmaxf(d2, 0.0f);
  float kv = os * expf((-0.5f * d2) / (ls * ls));
  K[(size_t)i * NPTS + j] = kv;
  Ld[(size_t)i * NPTS + j] = (double)kv + (i == j ? 1e-6 : 0.0);
}

__global__ __launch_bounds__(256) void k_castL(const double* Ld, float* Lf){
  int idx = blockIdx.x * 256 + threadIdx.x;
  int i = idx >> 10, j = idx & 1023;
  Lf[idx] = (j <= i) ? (float)Ld[idx] : 0.0f;
}

// ---------------- blocked Cholesky (templated, batched, in-place, lower) ----------------
template<typename T, int BS>
__global__ __launch_bounds__(256) void k_chol_diag(T* A, int k0){
  T* M = A + (size_t)blockIdx.x * NPTS * NPTS;
  __shared__ T t[BS][BS + 1];
  int tid = threadIdx.x;
  for (int idx = tid; idx < BS * BS; idx += 256){
    int r = idx / BS, c = idx - r * BS;
    t[r][c] = (c <= r) ? M[(size_t)(k0 + r) * NPTS + k0 + c] : (T)0;
  }
  __syncthreads();
  const int GROUPS = 256 / BS;
  int tr = tid % BS, tg = tid / BS;
  for (int j = 0; j < BS; ++j){
    __syncthreads();
    T piv = tsqrt(tmax(t[j][j], (T)1e-30));
    T inv = (T)1 / piv;
    __syncthreads();
    if (tid == 0) t[j][j] = piv;
    for (int r = j + 1 + tid; r < BS; r += 256) t[r][j] *= inv;
    __syncthreads();
    for (int r = j + 1 + tg; r < BS; r += GROUPS){
      int c = j + 1 + tr;
      if (c <= r) t[r][c] -= t[r][j] * t[c][j];
    }
  }
  __syncthreads();
  for (int idx = tid; idx < BS * BS; idx += 256){
    int r = idx / BS, c = idx - r * BS;
    M[(size_t)(k0 + r) * NPTS + k0 + c] = (c <= r) ? t[r][c] : (T)0;
  }
}

template<typename T, int BS>
__global__ void k_chol_panel(T* A, int k0){
  T* M = A + (size_t)blockIdx.y * NPTS * NPTS;
  __shared__ T D[BS][BS + 1];
  __shared__ T R[BS][BS + 1];
  int lane = threadIdx.x;             // blockDim = BS
  int r0 = k0 + BS + blockIdx.x * BS;
  for (int idx = lane; idx < BS * BS; idx += BS){
    int r = idx / BS, c = idx - r * BS;
    D[r][c] = M[(size_t)(k0 + r) * NPTS + k0 + c];
    R[r][c] = M[(size_t)(r0 + r) * NPTS + k0 + c];
  }
  __syncthreads();
  for (int j = 0; j < BS; ++j){
    T s = R[lane][j];
    for (int k = 0; k < j; ++k) s -= R[lane][k] * D[j][k];
    R[lane][j] = s / D[j][j];
  }
  __syncthreads();
  for (int idx = lane; idx < BS * BS; idx += BS){
    int r = idx / BS, c = idx - r * BS;
    M[(size_t)(r0 + r) * NPTS + k0 + c] = R[r][c];
  }
}

template<typename T, int TS>
__global__ __launch_bounds__(256) void k_chol_update(T* A, int k0){
  T* M = A + (size_t)blockIdx.y * NPTS * NPTS;
  const int MICRO = TS / 16;
  __shared__ T Pa[TS][TS + 1];
  __shared__ T Pb[TS][TS + 1];
  int ti, tj; tri_decode(blockIdx.x, ti, tj);
  int bi = k0 + TS + ti * TS;
  int bj = k0 + TS + tj * TS;
  int tid = threadIdx.x;
  for (int idx = tid; idx < TS * TS; idx += 256){
    int r = idx / TS, c = idx - r * TS;
    Pa[r][c] = M[(size_t)(bi + r) * NPTS + k0 + c];
    Pb[r][c] = M[(size_t)(bj + r) * NPTS + k0 + c];
  }
  __syncthreads();
  int tx = tid & 15, ty = tid >> 4;
  T acc[MICRO][MICRO];
#pragma unroll
  for (int a = 0; a < MICRO; ++a)
#pragma unroll
    for (int b = 0; b < MICRO; ++b) acc[a][b] = (T)0;
  for (int k = 0; k < TS; ++k){
    T av[MICRO], bv[MICRO];
#pragma unroll
    for (int a = 0; a < MICRO; ++a) av[a] = Pa[ty * MICRO + a][k];
#pragma unroll
    for (int b = 0; b < MICRO; ++b) bv[b] = Pb[tx * MICRO + b][k];
#pragma unroll
    for (int a = 0; a < MICRO; ++a)
#pragma unroll
      for (int b = 0; b < MICRO; ++b) acc[a][b] += av[a] * bv[b];
  }
#pragma unroll
  for (int a = 0; a < MICRO; ++a)
#pragma unroll
    for (int b = 0; b < MICRO; ++b){
      int gi = bi + ty * MICRO + a, gj = bj + tx * MICRO + b;
      M[(size_t)gi * NPTS + gj] -= acc[a][b];
    }
}

template<typename T, int BS>
static void run_chol(T* A, int batch, hipStream_t s){
  int nblocks = NPTS / BS;
  for (int p = 0; p < nblocks; ++p){
    int k0 = p * BS;
    k_chol_diag<T, BS><<<dim3(batch), 256, 0, s>>>(A, k0);
    int rows = NPTS - k0 - BS;
    if (rows > 0){
      k_chol_panel<T, BS><<<dim3(rows / BS, batch), BS, 0, s>>>(A, k0);
      int nt = rows / BS;
      k_chol_update<T, BS><<<dim3(nt * (nt + 1) / 2, batch), 256, 0, s>>>(A, k0);
    }
  }
}

// ---------------- triangular inverse (f32, 64-blocks) ----------------
__global__ void k_trinv_diag(const float* Lm, float* Li){
  const float* M = Lm + (size_t)blockIdx.y * NPTS * NPTS;
  float* O = Li + (size_t)blockIdx.y * NPTS * NPTS;
  int k0 = blockIdx.x * 64;
  __shared__ float L[64][65];
  __shared__ float Xs[64][65];
  int lane = threadIdx.x;   // blockDim = 64
  for (int idx = lane; idx < 64 * 64; idx += 64){
    int r = idx / 64, c = idx - r * 64;
    L[r][c] = M[(size_t)(k0 + r) * NPTS + k0 + c];
    Xs[r][c] = 0.f;
  }
  __syncthreads();
  int c = lane;
  Xs[c][c] = 1.0f / L[c][c];
  for (int r = c + 1; r < 64; ++r){
    float s = 0.f;
    for (int k = c; k < r; ++k) s += L[r][k] * Xs[k][c];
    Xs[r][c] = -s / L[r][r];
  }
  __syncthreads();
  for (int idx = lane; idx < 64 * 64; idx += 64){
    int r = idx / 64, c2 = idx - r * 64;
    O[(size_t)(k0 + r) * NPTS + k0 + c2] = Xs[r][c2];
  }
}

__global__ __launch_bounds__(256) void k_trinv_off(const float* Lm, float* Li, int lev){
  const float* M = Lm + (size_t)blockIdx.y * NPTS * NPTS;
  float* O = Li + (size_t)blockIdx.y * NPTS * NPTS;
  int J = blockIdx.x, I = J + lev;
  __shared__ float Ta[64][65];
  __shared__ float Tb[64][65];
  __shared__ float Gs[64][65];
  int tid = threadIdx.x, tx = tid & 15, ty = tid >> 4;
  float acc[4][4];
#pragma unroll
  for (int a = 0; a < 4; ++a)
#pragma unroll
    for (int b = 0; b < 4; ++b) acc[a][b] = 0.f;
  for (int K = J; K < I; ++K){
    __syncthreads();
    for (int idx = tid; idx < 64 * 64; idx += 256){
      int r = idx / 64, c = idx - r * 64;
      Ta[r][c] = M[(size_t)(I * 64 + r) * NPTS + K * 64 + c];
      Tb[r][c] = O[(size_t)(K * 64 + r) * NPTS + J * 64 + c];
    }
    __syncthreads();
    for (int k = 0; k < 64; ++k){
      float av[4], bv[4];
#pragma unroll
      for (int a = 0; a < 4; ++a) av[a] = Ta[ty * 4 + a][k];
#pragma unroll
      for (int b = 0; b < 4; ++b) bv[b] = Tb[k][tx * 4 + b];
#pragma unroll
      for (int a = 0; a < 4; ++a)
#pragma unroll
        for (int b = 0; b < 4; ++b) acc[a][b] += av[a] * bv[b];
    }
  }
  __syncthreads();
#pragma unroll
  for (int a = 0; a < 4; ++a)
#pragma unroll
    for (int b = 0; b < 4; ++b) Gs[ty * 4 + a][tx * 4 + b] = acc[a][b];
  for (int idx = tid; idx < 64 * 64; idx += 256){
    int r = idx / 64, c = idx - r * 64;
    Ta[r][c] = O[(size_t)(I * 64 + r) * NPTS + I * 64 + c];   // Dinv block
  }
  __syncthreads();
  float ac2[4][4];
#pragma unroll
  for (int a = 0; a < 4; ++a)
#pragma unroll
    for (int b = 0; b < 4; ++b) ac2[a][b] = 0.f;
  for (int k = 0; k < 64; ++k){
    float av[4], bv[4];
#pragma unroll
    for (int a = 0; a < 4; ++a) av[a] = Ta[ty * 4 + a][k];
#pragma unroll
    for (int b = 0; b < 4; ++b) bv[b] = Gs[k][tx * 4 + b];
#pragma unroll
    for (int a = 0; a < 4; ++a)
#pragma unroll
      for (int b = 0; b < 4; ++b) ac2[a][b] += av[a] * bv[b];
  }
#pragma unroll
  for (int a = 0; a < 4; ++a)
#pragma unroll
    for (int b = 0; b < 4; ++b)
      O[(size_t)(I * 64 + ty * 4 + a) * NPTS + J * 64 + tx * 4 + b] = -ac2[a][b];
}

// ---------------- M = I + L^T diag(omega) L  (lower tiles) ----------------
__global__ __launch_bounds__(256) void k_build_M(const float* Lf, const float* omega, float* Mb, int c0){
  float* M = Mb + (size_t)blockIdx.y * NPTS * NPTS;
  const float* om = omega + (size_t)(c0 + blockIdx.y) * NPTS;
  int ti, tj; tri_decode(blockIdx.x, ti, tj);
  __shared__ float Sa[32][65];
  __shared__ float Sb[32][65];
  int tid = threadIdx.x, tx = tid & 15, ty = tid >> 4;
  float acc[4][4];
#pragma unroll
  for (int a = 0; a < 4; ++a)
#pragma unroll
    for (int b = 0; b < 4; ++b) acc[a][b] = 0.f;
  for (int n0 = ti * 64; n0 < NPTS; n0 += 32){
    __syncthreads();
    for (int idx = tid; idx < 32 * 64; idx += 256){
      int r = idx >> 6, c = idx & 63;
      float w = om[n0 + r];
      Sa[r][c] = w * Lf[(size_t)(n0 + r) * NPTS + ti * 64 + c];
      Sb[r][c] = Lf[(size_t)(n0 + r) * NPTS + tj * 64 + c];
    }
    __syncthreads();
    for (int k = 0; k < 32; ++k){
      float av[4], bv[4];
#pragma unroll
      for (int a = 0; a < 4; ++a) av[a] = Sa[k][ty * 4 + a];
#pragma unroll
      for (int b = 0; b < 4; ++b) bv[b] = Sb[k][tx * 4 + b];
#pragma unroll
      for (int a = 0; a < 4; ++a)
#pragma unroll
        for (int b = 0; b < 4; ++b) acc[a][b] += av[a] * bv[b];
    }
  }
#pragma unroll
  for (int a = 0; a < 4; ++a)
#pragma unroll
    for (int b = 0; b < 4; ++b){
      int gi = ti * 64 + ty * 4 + a, gj = tj * 64 + tx * 4 + b;
      M[(size_t)gi * NPTS + gj] = acc[a][b] + (gi == gj ? 1.0f : 0.0f);
    }
}

// ---------------- W = Lf * Lminv^T (dense) ----------------
__global__ __launch_bounds__(256) void k_gemm_W(const float* Lf, const float* Li, float* W){
  const float* B = Li + (size_t)blockIdx.y * NPTS * NPTS;
  float* O = W + (size_t)blockIdx.y * NPTS * NPTS;
  int ti = blockIdx.x >> 4, tj = blockIdx.x & 15;
  int kmax = ti < tj ? ti : tj;
  __shared__ float Ta[64][65];
  __shared__ float Tb[64][65];
  int tid = threadIdx.x, tx = tid & 15, ty = tid >> 4;
  float acc[4][4];
#pragma unroll
  for (int a = 0; a < 4; ++a)
#pragma unroll
    for (int b = 0; b < 4; ++b) acc[a][b] = 0.f;
  for (int K = 0; K <= kmax; ++K){
    __syncthreads();
    for (int idx = tid; idx < 64 * 64; idx += 256){
      int r = idx / 64, c = idx - r * 64;
      Ta[r][c] = Lf[(size_t)(ti * 64 + r) * NPTS + K * 64 + c];
      Tb[r][c] = B[(size_t)(tj * 64 + r) * NPTS + K * 64 + c];
    }
    __syncthreads();
    for (int k = 0; k < 64; ++k){
      float av[4], bv[4];
#pragma unroll
      for (int a = 0; a < 4; ++a) av[a] = Ta[ty * 4 + a][k];
#pragma unroll
      for (int b = 0; b < 4; ++b) bv[b] = Tb[tx * 4 + b][k];
#pragma unroll
      for (int a = 0; a < 4; ++a)
#pragma unroll
        for (int b = 0; b < 4; ++b) acc[a][b] += av[a] * bv[b];
    }
  }
#pragma unroll
  for (int a = 0; a < 4; ++a)
#pragma unroll
    for (int b = 0; b < 4; ++b)
      O[(size_t)(ti * 64 + ty * 4 + a) * NPTS + tj * 64 + tx * 4 + b] = acc[a][b];
}

// ---------------- sigma = W W^T (+ jitter), lower tiles ----------------
__global__ __launch_bounds__(256) void k_syrk_sigma(const float* W, float* Sg){
  const float* A = W + (size_t)blockIdx.y * NPTS * NPTS;
  float* O = Sg + (size_t)blockIdx.y * NPTS * NPTS;
  int ti, tj; tri_decode(blockIdx.x, ti, tj);
  __shared__ float Ta[64][65];
  __shared__ float Tb[64][65];
  int tid = threadIdx.x, tx = tid & 15, ty = tid >> 4;
  float acc[4][4];
#pragma unroll
  for (int a = 0; a < 4; ++a)
#pragma unroll
    for (int b = 0; b < 4; ++b) acc[a][b] = 0.f;
  for (int K = 0; K < 16; ++K){
    __syncthreads();
    for (int idx = tid; idx < 64 * 64; idx += 256){
      int r = idx / 64, c = idx - r * 64;
      Ta[r][c] = A[(size_t)(ti * 64 + r) * NPTS + K * 64 + c];
      Tb[r][c] = A[(size_t)(tj * 64 + r) * NPTS + K * 64 + c];
    }
    __syncthreads();
    for (int k = 0; k < 64; ++k){
      float av[4], bv[4];
#pragma unroll
      for (int a = 0; a < 4; ++a) av[a] = Ta[ty * 4 + a][k];
#pragma unroll
      for (int b = 0; b < 4; ++b) bv[b] = Tb[tx * 4 + b][k];
#pragma unroll
      for (int a = 0; a < 4; ++a)
#pragma unroll
        for (int b = 0; b < 4; ++b) acc[a][b] += av[a] * bv[b];
    }
  }
#pragma unroll
  for (int a = 0; a < 4; ++a)
#pragma unroll
    for (int b = 0; b < 4; ++b){
      int gi = ti * 64 + ty * 4 + a, gj = tj * 64 + tx * 4 + b;
      O[(size_t)gi * NPTS + gj] = acc[a][b] + (gi == gj ? 1e-6f : 0.0f);
    }
}

// ---------------- small per-draw vector kernels ----------------
__global__ __launch_bounds__(256) void k_matvec_mu(const float* Sg, const float* kappa, float* mu, int c0){
  const float* S = Sg + (size_t)blockIdx.y * NPTS * NPTS;
  int i = blockIdx.x * 256 + threadIdx.x;
  float s = 0.f;
  for (int j = 0; j <= i; ++j) s += S[(size_t)i * NPTS + j] * kappa[j];
  for (int j = i + 1; j < NPTS; ++j) s += S[(size_t)j * NPTS + i] * kappa[j];
  mu[(size_t)(c0 + blockIdx.y) * NPTS + i] = s;
}

__global__ __launch_bounds__(256) void k_matvec_f(const float* Lt, const float* mu, const float* eps, float* f, int c0){
  const float* L = Lt + (size_t)blockIdx.y * NPTS * NPTS;
  int d = c0 + blockIdx.y;
  int i = blockIdx.x * 256 + threadIdx.x;
  float s = 0.f;
  for (int j = 0; j <= i; ++j) s += L[(size_t)i * NPTS + j] * eps[(size_t)d * NPTS + j];
  f[(size_t)d * NPTS + i] = mu[(size_t)d * NPTS + i] + s;
}

__global__ __launch_bounds__(256) void k_init_f(const float* Lf, const float* eps, float* f){
  int d = blockIdx.y;
  int i = blockIdx.x * 256 + threadIdx.x;
  float s = 0.f;
  for (int j = 0; j <= i; ++j) s += Lf[(size_t)i * NPTS + j] * eps[(size_t)d * NPTS + j];
  f[(size_t)d * NPTS + i] = s;
}

__global__ __launch_bounds__(256) void k_gen_eps(u32 ka, u32 kb, float* eps){
  int i = blockIdx.x * 256 + threadIdx.x;
  if (i >= NDRAWS * NPTS) return;
  u32 bits = rand32(ka, kb, (u32)i, (u32)(NDRAWS * NPTS));
  eps[i] = normal_from_bits(bits);
}

__global__ __launch_bounds__(256) void k_pg(u32 ka, u32 kb, const float* f, float* omega){
  int idx = blockIdx.x * 256 + threadIdx.x;
  if (idx >= NDRAWS * NPTS) return;
  float c = f[idx];
  float c2w = (c * c) / 39.47841760435743f;   // 4*pi^2
  float sum = 0.f;
  u32 base = (u32)idx * NG;
  for (int g = 0; g < NG; ++g){
    u32 bits = rand32(ka, kb, base + (u32)g, (u32)(NDRAWS * NPTS * NG));
    float u = u01f(bits);
    float e = -log1pf(-u);
    float kk = (float)g + 0.5f;
    sum += e / (kk * kk + c2w);
  }
  omega[idx] = sum / 19.739208802178716f;     // 2*pi^2
}

// ---------------- final mll ----------------
__global__ __launch_bounds__(256) void k_build_Sz(const float* K, const float* omega, float* A, int c0){
  float* M = A + (size_t)blockIdx.y * NPTS * NPTS;
  int d = c0 + blockIdx.y;
  int idx = blockIdx.x * 256 + threadIdx.x;
  int i = idx >> 10, j = idx & 1023;
  float v = K[idx];
  if (i == j){
    float om = fmaxf(omega[(size_t)d * NPTS + i], 1e-16f);
    v += 1.0f / om + 1e-6f;
  }
  M[idx] = v;
}

__global__ __launch_bounds__(256) void k_final(const float* Lz, const float* omega, const float* kappa, float* mll, int c0){
  const float* L = Lz + (size_t)blockIdx.x * NPTS * NPTS;
  int d = c0 + blockIdx.x;
  __shared__ float sol[NPTS];
  __shared__ float red[4];
  __shared__ float r4[4][4];
  int tid = threadIdx.x;
  int wid = tid >> 6, lane = tid & 63;
  for (int j = 0; j < NPTS; ++j){
    float part = 0.f;
    for (int k = tid; k < j; k += 256) part += L[(size_t)j * NPTS + k] * sol[k];
    for (int o = 32; o; o >>= 1) part += __shfl_down(part, o);
    if (lane == 0) red[wid] = part;
    __syncthreads();
    if (tid == 0){
      float s = red[0] + red[1] + red[2] + red[3];
      float om = fmaxf(omega[(size_t)d * NPTS + j], 1e-16f);
      float zj = kappa[j] / om;
      sol[j] = (zj - s) / L[(size_t)j * NPTS + j];
    }
    __syncthreads();
  }
  float q = 0.f, ld = 0.f, slo = 0.f, sko = 0.f;
  for (int j = tid; j < NPTS; j += 256){
    float sv = sol[j]; q += sv * sv;
    ld += logf(L[(size_t)j * NPTS + j]);
    float om = fmaxf(omega[(size_t)d * NPTS + j], 1e-16f);
    slo += logf(om);
    float kj = kappa[j];
    sko += kj * kj / om;
  }
  for (int o = 32; o; o >>= 1){
    q += __shfl_down(q, o); ld += __shfl_down(ld, o);
    slo += __shfl_down(slo, o); sko += __shfl_down(sko, o);
  }
  if (lane == 0){ r4[wid][0] = q; r4[wid][1] = ld; r4[wid][2] = slo; r4[wid][3] = sko; }
  __syncthreads();
  if (tid == 0){
    q = 0.f; ld = 0.f; slo = 0.f; sko = 0.f;
    for (int w = 0; w < 4; ++w){ q += r4[w][0]; ld += r4[w][1]; slo += r4[w][2]; sko += r4[w][3]; }
    mll[d] = -0.5f * q - ld - 0.5f * slo + 0.5f * sko - 709.7827128933839f;  // N*log(2)
  }
}

__global__ void k_out(const float* mll, float* out){
  if (threadIdx.x == 0){
    float s = 0.f;
    for (int dd = 0; dd < NDRAWS; ++dd) s += mll[dd];
    float m = s / (float)NDRAWS;
    out[0] = (-m) / (float)NPTS;
  }
}

// ---------------- host-side key derivation ----------------
static void host_split(u32 ka, u32 kb, int num, u32* outA, u32* outB){
#if PARTITIONABLE
  for (int j = 0; j < num; ++j) tf2x32(ka, kb, 0u, (u32)j, &outA[j], &outB[j]);
#else
  u32 flat[40];
  for (int k = 0; k < num; ++k){
    u32 a, b; tf2x32(ka, kb, (u32)k, (u32)(num + k), &a, &b);
    flat[k] = a; flat[num + k] = b;
  }
  for (int j = 0; j < num; ++j){ outA[j] = flat[2 * j]; outB[j] = flat[2 * j + 1]; }
#endif
}

extern "C" void kernel_launch(void* const* d_in, const int* in_sizes, int n_in,
                              void* d_out, int out_size, void* d_ws, size_t ws_size,
                              hipStream_t stream){
  const float* X  = (const float*)d_in[0];
  const int*   Y  = (const int*)d_in[1];
  const float* osp = (const float*)d_in[2];
  const float* lsp = (const float*)d_in[3];
  float* out = (float*)d_out;

  const size_t NN = (size_t)NPTS * NPTS;
  char* p = (char*)d_ws;
  float* K     = (float*)p;  p += NN * 4;
  float* Lf    = (float*)p;  p += NN * 4;
  double* Ld   = (double*)p; p += NN * 8;
  float* omega = (float*)p;  p += (size_t)NDRAWS * NPTS * 4;
  float* fbuf  = (float*)p;  p += (size_t)NDRAWS * NPTS * 4;
  float* epsb  = (float*)p;  p += (size_t)NDRAWS * NPTS * 4;
  float* mub   = (float*)p;  p += (size_t)NDRAWS * NPTS * 4;
  float* kappa = (float*)p;  p += NPTS * 4;
  float* x2    = (float*)p;  p += NPTS * 4;
  float* mll   = (float*)p;  p += NDRAWS * 4;
  uintptr_t ip = (uintptr_t)p; ip = (ip + 255) & ~(uintptr_t)255; p = (char*)ip;
  size_t used = (size_t)(p - (char*)d_ws);
  size_t rem = ws_size > used ? ws_size - used : 0;
  int CH = (int)(rem / (2 * NN * 4));
  if (CH > NDRAWS) CH = NDRAWS;
  if (CH < 1) CH = 1;
  float* buf1 = (float*)p;
  float* buf2 = buf1 + (size_t)CH * NN;

  // ---- keys (pure host arithmetic, identical every call) ----
  u32 r3A[3], r3B[3];
  host_split(0u, 42u, 3, r3A, r3B);
  u32 kiA = r3A[0], kiB = r3B[0];        // k_init
  u32 koA = r3A[1], koB = r3B[1];        // k_om0
  u32 klA = r3A[2], klB = r3B[2];        // k_loop
  u32 kkA[NSTEPS], kkB[NSTEPS];
  host_split(klA, klB, NSTEPS, kkA, kkB);
  u32 k1A[NSTEPS], k1B[NSTEPS], k2A[NSTEPS], k2B[NSTEPS];
  for (int t = 0; t < NSTEPS; ++t){
    u32 sA[2], sB[2];
    host_split(kkA[t], kkB[t], 2, sA, sB);
    k1A[t] = sA[0]; k1B[t] = sB[0];
    k2A[t] = sA[1]; k2B[t] = sB[1];
  }

  // ---- setup ----
  k_prep<<<dim3(4), 256, 0, stream>>>(X, Y, x2, kappa);
  k_computeK<<<dim3(64, 64), dim3(16, 16), 0, stream>>>(X, x2, osp, lsp, K, Ld);
  run_chol<double, 32>(Ld, 1, stream);
  k_castL<<<dim3(4096), 256, 0, stream>>>(Ld, Lf);

  k_gen_eps<<<dim3(80), 256, 0, stream>>>(kiA, kiB, epsb);
  k_init_f<<<dim3(4, NDRAWS), 256, 0, stream>>>(Lf, epsb, fbuf);
  k_pg<<<dim3(80), 256, 0, stream>>>(koA, koB, fbuf, omega);

  // ---- Gibbs steps ----
  for (int t = 0; t < NSTEPS; ++t){
    k_gen_eps<<<dim3(80), 256, 0, stream>>>(k1A[t], k1B[t], epsb);
    for (int c0 = 0; c0 < NDRAWS; c0 += CH){
      int nb = NDRAWS - c0 < CH ? NDRAWS - c0 : CH;
      k_build_M<<<dim3(136, nb), 256, 0, stream>>>(Lf, omega, buf1, c0);
      run_chol<float, 64>(buf1, nb, stream);
      k_trinv_diag<<<dim3(16, nb), 64, 0, stream>>>(buf1, buf2);
      for (int lev = 1; lev < 16; ++lev)
        k_trinv_off<<<dim3(16 - lev, nb), 256, 0, stream>>>(buf1, buf2, lev);
      k_gemm_W<<<dim3(256, nb), 256, 0, stream>>>(Lf, buf2, buf1);       // W -> buf1
      k_syrk_sigma<<<dim3(136, nb), 256, 0, stream>>>(buf1, buf2);       // sigma -> buf2
      k_matvec_mu<<<dim3(4, nb), 256, 0, stream>>>(buf2, kappa, mub, c0);
      run_chol<float, 64>(buf2, nb, stream);                             // Lt in place
      k_matvec_f<<<dim3(4, nb), 256, 0, stream>>>(buf2, mub, epsb, fbuf, c0);
    }
    k_pg<<<dim3(80), 256, 0, stream>>>(k2A[t], k2B[t], fbuf, omega);
  }

  // ---- final mll ----
  for (int c0 = 0; c0 < NDRAWS; c0 += CH){
    int nb = NDRAWS - c0 < CH ? NDRAWS - c0 : CH;
    k_build_Sz<<<dim3(4096, nb), 256, 0, stream>>>(K, omega, buf1, c0);
    run_chol<float, 64>(buf1, nb, stream);
    k_final<<<dim3(nb), 256, 0, stream>>>(buf1, omega, kappa, mll, c0);
  }
  k_out<<<dim3(1), 64, 0, stream>>>(mll, out);
}

// Round 2
// 36888.586 us; speedup vs baseline: 2.1451x; 2.1451x over previous
//
#include <hip/hip_runtime.h>
#include <stdint.h>

#define NPTS 1024
#define NDRAWS 20
#define NSTEPS 10
#define NG 100
#define PARTITIONABLE 1

typedef unsigned int u32;

// ---------------- threefry2x32 (JAX-compatible, 20 rounds) ----------------
__host__ __device__ static inline void tf2x32(u32 k0, u32 k1, u32 x0, u32 x1, u32* o0, u32* o1){
  u32 ks2 = k0 ^ k1 ^ 0x1BD11BDAu;
  x0 += k0; x1 += k1;
#define TFR(r) { x0 += x1; x1 = (x1 << r) | (x1 >> (32 - r)); x1 ^= x0; }
  TFR(13) TFR(15) TFR(26) TFR(6)
  x0 += k1; x1 += ks2 + 1u;
  TFR(17) TFR(29) TFR(16) TFR(24)
  x0 += ks2; x1 += k0 + 2u;
  TFR(13) TFR(15) TFR(26) TFR(6)
  x0 += k0; x1 += k1 + 3u;
  TFR(17) TFR(29) TFR(16) TFR(24)
  x0 += k1; x1 += ks2 + 4u;
  TFR(13) TFR(15) TFR(26) TFR(6)
  x0 += ks2; x1 += k0 + 5u;
#undef TFR
  *o0 = x0; *o1 = x1;
}

__device__ static inline u32 rand32(u32 ka, u32 kb, u32 i, u32 total){
  u32 a, b;
#if PARTITIONABLE
  (void)total;
  tf2x32(ka, kb, 0u, i, &a, &b);
  return a ^ b;
#else
  u32 h = total >> 1;
  if (i < h){ tf2x32(ka, kb, i, i + h, &a, &b); return a; }
  else      { tf2x32(ka, kb, i - h, i, &a, &b); return b; }
#endif
}

__device__ static inline float u01f(u32 bits){
  return __uint_as_float(0x3F800000u | (bits >> 9)) - 1.0f;
}

// XLA ErfInv32 (Giles) polynomial — matches jax.lax.erf_inv for f32
__device__ static inline float erfinv32(float x){
  float w = -log1pf(-x * x);
  float p;
  if (w < 5.0f){
    w -= 2.5f;
    p = 2.81022636e-08f;
    p = fmaf(p, w, 3.43273939e-07f);
    p = fmaf(p, w, -3.5233877e-06f);
    p = fmaf(p, w, -4.39150654e-06f);
    p = fmaf(p, w, 0.00021858087f);
    p = fmaf(p, w, -0.00125372503f);
    p = fmaf(p, w, -0.00417768164f);
    p = fmaf(p, w, 0.246640727f);
    p = fmaf(p, w, 1.50140941f);
  } else {
    w = sqrtf(w) - 3.0f;
    p = -0.000200214257f;
    p = fmaf(p, w, 0.000100950558f);
    p = fmaf(p, w, 0.00134934322f);
    p = fmaf(p, w, -0.00367342844f);
    p = fmaf(p, w, 0.00573950773f);
    p = fmaf(p, w, -0.0076224613f);
    p = fmaf(p, w, 0.00943887047f);
    p = fmaf(p, w, 1.00167406f);
    p = fmaf(p, w, 2.83297682f);
  }
  return p * x;
}

__device__ static inline float normal_from_bits(u32 bits){
  const float LO = -0.99999994f;
  float u = u01f(bits);
  float v = u * 2.0f + LO;
  v = fmaxf(LO, v);
  return 1.4142135623730951f * erfinv32(v);
}

__device__ inline float  tsqrt(float x){ return sqrtf(x); }
__device__ inline double tsqrt(double x){ return sqrt(x); }
__device__ inline float  tmax(float a, float b){ return fmaxf(a, b); }
__device__ inline double tmax(double a, double b){ return fmax(a, b); }

__device__ inline void tri_decode(int p, int& ti, int& tj){
  int t = (int)((sqrtf(8.0f * (float)p + 1.0f) - 1.0f) * 0.5f);
  while ((t + 1) * (t + 2) / 2 <= p) ++t;
  while (t * (t + 1) / 2 > p) --t;
  ti = t; tj = p - t * (t + 1) / 2;
}

// ---------------- setup kernels ----------------
__global__ __launch_bounds__(256) void k_prep(const float* X, const int* Y, float* x2,
                                              float* kappa, float* kappaf){
  int n = blockIdx.x * 256 + threadIdx.x;
  if (n >= NPTS) return;
  float s = 0.f;
  for (int d = 0; d < 64; ++d){ float v = X[n * 64 + d]; s += v * v; }
  x2[n] = s;
  float kv = (float)Y[n] - 0.5f;
  kappa[n] = kv;
  kappaf[NPTS - 1 - n] = kv;
}

__global__ void k_computeK(const float* X, const float* x2, const float* osp, const float* lsp,
                           float* K, double* Ld){
  int j = blockIdx.x * 16 + threadIdx.x;
  int i = blockIdx.y * 16 + threadIdx.y;
  float os = osp[0], ls = lsp[0];
  float dot = 0.f;
  for (int d = 0; d < 64; ++d) dot += X[i * 64 + d] * X[j * 64 + d];
  float d2 = x2[i] + x2[j] - 2.0f * dot;
  d2 = fmaxf(d2, 0.0f);
  float kv = os * expf((-0.5f * d2) / (ls * ls));
  K[(size_t)i * NPTS + j] = kv;
  Ld[(size_t)i * NPTS + j] = (double)kv + (i == j ? 1e-6 : 0.0);
}

__global__ __launch_bounds__(256) void k_castL(const double* Ld, float* Lf){
  int idx = blockIdx.x * 256 + threadIdx.x;
  int i = idx >> 10, j = idx & 1023;
  Lf[idx] = (j <= i) ? (float)Ld[idx] : 0.0f;
}

// ---------------- blocked Cholesky with diag-block inverse production ----------------
// Diag: chol of 64x64 block in LDS, write L back, compute inv(Lpp) -> Dinv[p]
template<typename T>
__global__ __launch_bounds__(256) void k_chol_diag_inv(T* A, T* Dinv, int p){
  T* M = A + (size_t)blockIdx.x * NPTS * NPTS;
  T* DI = Dinv + ((size_t)blockIdx.x * 16 + p) * 4096;
  int k0 = p * 64;
  __shared__ T t[64][65];
  __shared__ T Xs[64][65];
  int tid = threadIdx.x;
  for (int idx = tid; idx < 4096; idx += 256){
    int r = idx >> 6, c = idx & 63;
    t[r][c] = (c <= r) ? M[(size_t)(k0 + r) * NPTS + k0 + c] : (T)0;
    Xs[r][c] = (T)0;
  }
  __syncthreads();
  for (int j = 0; j < 64; ++j){
    T piv = tsqrt(tmax(t[j][j], (T)1e-30));
    T inv = (T)1 / piv;
    __syncthreads();
    if (tid == 0) t[j][j] = piv;
    for (int r = j + 1 + tid; r < 64; r += 256) t[r][j] *= inv;
    __syncthreads();
    int tr = tid & 63, tg = tid >> 6;
    for (int r = j + 1 + tg; r < 64; r += 4){
      int c = j + 1 + tr;
      if (c <= r) t[r][c] -= t[r][j] * t[c][j];
    }
    __syncthreads();
  }
  // write L block back
  for (int idx = tid; idx < 4096; idx += 256){
    int r = idx >> 6, c = idx & 63;
    M[(size_t)(k0 + r) * NPTS + k0 + c] = (c <= r) ? t[r][c] : (T)0;
  }
  // inverse of lower-triangular t, column per thread
  if (tid < 64){
    int c = tid;
    Xs[c][c] = (T)1 / t[c][c];
    for (int r = c + 1; r < 64; ++r){
      T s = (T)0;
      for (int k = c; k < r; ++k) s += t[r][k] * Xs[k][c];
      Xs[r][c] = -s / t[r][r];
    }
  }
  __syncthreads();
  for (int idx = tid; idx < 4096; idx += 256){
    int r = idx >> 6, c = idx & 63;
    DI[idx] = Xs[r][c];
  }
}

// Panel: R <- R * Dinv^T  (pure GEMM against stored diag inverse)
template<typename T>
__global__ __launch_bounds__(256) void k_chol_panel_gemm(T* A, const T* Dinv, int p){
  T* M = A + (size_t)blockIdx.y * NPTS * NPTS;
  const T* DI = Dinv + ((size_t)blockIdx.y * 16 + p) * 4096;
  int r0 = (p + 1) * 64 + blockIdx.x * 64;
  __shared__ T Rs[64][65];
  __shared__ T Ds[64][65];
  int tid = threadIdx.x;
  for (int idx = tid; idx < 4096; idx += 256){
    int r = idx >> 6, c = idx & 63;
    Rs[r][c] = M[(size_t)(r0 + r) * NPTS + p * 64 + c];
    Ds[r][c] = DI[idx];
  }
  __syncthreads();
  int tx = tid & 15, ty = tid >> 4;
  T acc[4][4];
#pragma unroll
  for (int a = 0; a < 4; ++a)
#pragma unroll
    for (int b = 0; b < 4; ++b) acc[a][b] = (T)0;
  for (int k = 0; k < 64; ++k){
    T av[4], bv[4];
#pragma unroll
    for (int a = 0; a < 4; ++a) av[a] = Rs[ty * 4 + a][k];
#pragma unroll
    for (int b = 0; b < 4; ++b) bv[b] = Ds[tx * 4 + b][k];
#pragma unroll
    for (int a = 0; a < 4; ++a)
#pragma unroll
      for (int b = 0; b < 4; ++b) acc[a][b] += av[a] * bv[b];
  }
#pragma unroll
  for (int a = 0; a < 4; ++a)
#pragma unroll
    for (int b = 0; b < 4; ++b)
      M[(size_t)(r0 + ty * 4 + a) * NPTS + p * 64 + tx * 4 + b] = acc[a][b];
}

// Trailing update: M[bi][bj] -= P_bi * P_bj^T
template<typename T>
__global__ __launch_bounds__(256) void k_chol_update(T* A, int k0){
  T* M = A + (size_t)blockIdx.y * NPTS * NPTS;
  __shared__ T Pa[64][65];
  __shared__ T Pb[64][65];
  int ti, tj; tri_decode(blockIdx.x, ti, tj);
  int bi = k0 + 64 + ti * 64;
  int bj = k0 + 64 + tj * 64;
  int tid = threadIdx.x;
  for (int idx = tid; idx < 4096; idx += 256){
    int r = idx >> 6, c = idx & 63;
    Pa[r][c] = M[(size_t)(bi + r) * NPTS + k0 + c];
    Pb[r][c] = M[(size_t)(bj + r) * NPTS + k0 + c];
  }
  __syncthreads();
  int tx = tid & 15, ty = tid >> 4;
  T acc[4][4];
#pragma unroll
  for (int a = 0; a < 4; ++a)
#pragma unroll
    for (int b = 0; b < 4; ++b) acc[a][b] = (T)0;
  for (int k = 0; k < 64; ++k){
    T av[4], bv[4];
#pragma unroll
    for (int a = 0; a < 4; ++a) av[a] = Pa[ty * 4 + a][k];
#pragma unroll
    for (int b = 0; b < 4; ++b) bv[b] = Pb[tx * 4 + b][k];
#pragma unroll
    for (int a = 0; a < 4; ++a)
#pragma unroll
      for (int b = 0; b < 4; ++b) acc[a][b] += av[a] * bv[b];
  }
#pragma unroll
  for (int a = 0; a < 4; ++a)
#pragma unroll
    for (int b = 0; b < 4; ++b){
      int gi = bi + ty * 4 + a, gj = bj + tx * 4 + b;
      M[(size_t)gi * NPTS + gj] -= acc[a][b];
    }
}

template<typename T>
static void run_chol(T* A, T* Dinv, int batch, hipStream_t s){
  for (int p = 0; p < 16; ++p){
    k_chol_diag_inv<T><<<dim3(batch), 256, 0, s>>>(A, Dinv, p);
    int nrb = 15 - p;
    if (nrb > 0){
      k_chol_panel_gemm<T><<<dim3(nrb, batch), 256, 0, s>>>(A, Dinv, p);
      k_chol_update<T><<<dim3(nrb * (nrb + 1) / 2, batch), 256, 0, s>>>(A, p * 64);
    }
  }
}

// ---------------- f64 triangular inverse (one-time, for Kinv) ----------------
__global__ __launch_bounds__(256) void k_trinv_copy_diag(const double* DinvD, double* Td){
  int p = blockIdx.x;
  for (int idx = threadIdx.x; idx < 4096; idx += 256){
    int r = idx >> 6, c = idx & 63;
    Td[(size_t)(p * 64 + r) * NPTS + p * 64 + c] = DinvD[(size_t)p * 4096 + idx];
  }
}

__global__ __launch_bounds__(256) void k_trinv_off_d(const double* Lm, double* Li, int lev){
  const double* M = Lm;
  double* O = Li;
  int J = blockIdx.x, I = J + lev;
  __shared__ double Ta[64][65];
  __shared__ double Tb[64][65];
  int tid = threadIdx.x, tx = tid & 15, ty = tid >> 4;
  double acc[4][4];
#pragma unroll
  for (int a = 0; a < 4; ++a)
#pragma unroll
    for (int b = 0; b < 4; ++b) acc[a][b] = 0.0;
  for (int K = J; K < I; ++K){
    __syncthreads();
    for (int idx = tid; idx < 4096; idx += 256){
      int r = idx >> 6, c = idx & 63;
      Ta[r][c] = M[(size_t)(I * 64 + r) * NPTS + K * 64 + c];
      Tb[r][c] = O[(size_t)(K * 64 + r) * NPTS + J * 64 + c];
    }
    __syncthreads();
    for (int k = 0; k < 64; ++k){
      double av[4], bv[4];
#pragma unroll
      for (int a = 0; a < 4; ++a) av[a] = Ta[ty * 4 + a][k];
#pragma unroll
      for (int b = 0; b < 4; ++b) bv[b] = Tb[k][tx * 4 + b];
#pragma unroll
      for (int a = 0; a < 4; ++a)
#pragma unroll
        for (int b = 0; b < 4; ++b) acc[a][b] += av[a] * bv[b];
    }
  }
  __syncthreads();
  // G in LDS (reuse Tb), then out = -Dinv_I * G
#pragma unroll
  for (int a = 0; a < 4; ++a)
#pragma unroll
    for (int b = 0; b < 4; ++b) Tb[ty * 4 + a][tx * 4 + b] = acc[a][b];
  for (int idx = tid; idx < 4096; idx += 256){
    int r = idx >> 6, c = idx & 63;
    Ta[r][c] = O[(size_t)(I * 64 + r) * NPTS + I * 64 + c];
  }
  __syncthreads();
  double ac2[4][4];
#pragma unroll
  for (int a = 0; a < 4; ++a)
#pragma unroll
    for (int b = 0; b < 4; ++b) ac2[a][b] = 0.0;
  for (int k = 0; k < 64; ++k){
    double av[4], bv[4];
#pragma unroll
    for (int a = 0; a < 4; ++a) av[a] = Ta[ty * 4 + a][k];
#pragma unroll
    for (int b = 0; b < 4; ++b) bv[b] = Tb[k][tx * 4 + b];
#pragma unroll
    for (int a = 0; a < 4; ++a)
#pragma unroll
      for (int b = 0; b < 4; ++b) ac2[a][b] += av[a] * bv[b];
  }
#pragma unroll
  for (int a = 0; a < 4; ++a)
#pragma unroll
    for (int b = 0; b < 4; ++b)
      O[(size_t)(I * 64 + ty * 4 + a) * NPTS + J * 64 + tx * 4 + b] = -ac2[a][b];
}

// Kinvf[i][j] = (float)(Td^T Td)[1023-i][1023-j]   (flipped inverse of K+jI)
__global__ __launch_bounds__(256) void k_syrk_kinv_flip(const double* Td, float* Kinvf){
  int ti = blockIdx.x >> 4, tj = blockIdx.x & 15;
  int kmin = ti > tj ? ti : tj;
  __shared__ double Ta[64][65];
  __shared__ double Tb[64][65];
  int tid = threadIdx.x, tx = tid & 15, ty = tid >> 4;
  double acc[4][4];
#pragma unroll
  for (int a = 0; a < 4; ++a)
#pragma unroll
    for (int b = 0; b < 4; ++b) acc[a][b] = 0.0;
  for (int K = kmin; K < 16; ++K){
    __syncthreads();
    for (int idx = tid; idx < 4096; idx += 256){
      int r = idx >> 6, c = idx & 63;
      Ta[r][c] = Td[(size_t)(K * 64 + r) * NPTS + ti * 64 + c];
      Tb[r][c] = Td[(size_t)(K * 64 + r) * NPTS + tj * 64 + c];
    }
    __syncthreads();
    for (int k = 0; k < 64; ++k){
      double av[4], bv[4];
#pragma unroll
      for (int a = 0; a < 4; ++a) av[a] = Ta[k][ty * 4 + a];
#pragma unroll
      for (int b = 0; b < 4; ++b) bv[b] = Tb[k][tx * 4 + b];
#pragma unroll
      for (int a = 0; a < 4; ++a)
#pragma unroll
        for (int b = 0; b < 4; ++b) acc[a][b] += av[a] * bv[b];
    }
  }
#pragma unroll
  for (int a = 0; a < 4; ++a)
#pragma unroll
    for (int b = 0; b < 4; ++b){
      int gi = ti * 64 + ty * 4 + a, gj = tj * 64 + tx * 4 + b;
      Kinvf[(size_t)(NPTS - 1 - gi) * NPTS + (NPTS - 1 - gj)] = (float)acc[a][b];
    }
}

// ---------------- per-step kernels ----------------
__global__ __launch_bounds__(256) void k_buildA(const float* Kinvf, const float* omega, float* Ab, int c0){
  int d = c0 + blockIdx.y;
  float* A = Ab + (size_t)blockIdx.y * NPTS * NPTS;
  int idx = blockIdx.x * 256 + threadIdx.x;
  int i = idx >> 10, j = idx & 1023;
  float v = Kinvf[idx];
  if (i == j) v += omega[(size_t)d * NPTS + (NPTS - 1 - i)];
  A[idx] = v;
}

// forward solve: Lb z = kappaf  ->  zbuf (per chunk draw)
__global__ __launch_bounds__(256) void k_fwd_solve(const float* Ab, const float* DinvF,
                                                   const float* kappaf, float* zbuf){
  int d0 = blockIdx.x;
  const float* L = Ab + (size_t)d0 * NPTS * NPTS;
  const float* DI = DinvF + (size_t)d0 * 16 * 4096;
  __shared__ float z[NPTS];
  __shared__ float tile[64][65];
  __shared__ float part[4][64];
  int tid = threadIdx.x;
  for (int i = tid; i < NPTS; i += 256) z[i] = kappaf[i];
  __syncthreads();
  for (int p = 0; p < 16; ++p){
    for (int idx = tid; idx < 4096; idx += 256)
      tile[idx >> 6][idx & 63] = DI[p * 4096 + idx];
    __syncthreads();
    {
      int r = tid & 63, q = tid >> 6;
      float s = 0.f;
#pragma unroll
      for (int cc = 0; cc < 16; ++cc){
        int c = q * 16 + cc;
        s += tile[r][c] * z[p * 64 + c];
      }
      part[q][r] = s;
    }
    __syncthreads();
    float zn = 0.f;
    if (tid < 64) zn = part[0][tid] + part[1][tid] + part[2][tid] + part[3][tid];
    __syncthreads();
    if (tid < 64) z[p * 64 + tid] = zn;
    __syncthreads();
    for (int rb = p + 1; rb < 16; ++rb){
      for (int idx = tid; idx < 4096; idx += 256)
        tile[idx >> 6][idx & 63] = L[(size_t)(rb * 64 + (idx >> 6)) * NPTS + p * 64 + (idx & 63)];
      __syncthreads();
      int r = tid & 63, q = tid >> 6;
      float s = 0.f;
#pragma unroll
      for (int cc = 0; cc < 16; ++cc){
        int c = q * 16 + cc;
        s += tile[r][c] * z[p * 64 + c];
      }
      part[q][r] = s;
      __syncthreads();
      if (tid < 64) z[rb * 64 + tid] -= part[0][tid] + part[1][tid] + part[2][tid] + part[3][tid];
      __syncthreads();
    }
  }
  for (int i = tid; i < NPTS; i += 256) zbuf[(size_t)d0 * NPTS + i] = z[i];
}

// back solve with 2 RHS: y1 = Lb^-T z (mu path), y2 = Lb^-T (P eps); f = P(y1+y2)
__global__ __launch_bounds__(256) void k_back_solve_f(const float* Ab, const float* DinvF,
                                                      const float* zbuf, const float* eps,
                                                      float* fbuf, int c0){
  int d0 = blockIdx.x, d = c0 + d0;
  const float* L = Ab + (size_t)d0 * NPTS * NPTS;
  const float* DI = DinvF + (size_t)d0 * 16 * 4096;
  __shared__ float z1[NPTS], z2[NPTS];
  __shared__ float tile[64][65];
  __shared__ float p1[4][64], p2[4][64];
  int tid = threadIdx.x;
  for (int i = tid; i < NPTS; i += 256){
    z1[i] = zbuf[(size_t)d0 * NPTS + i];
    z2[NPTS - 1 - i] = eps[(size_t)d * NPTS + i];
  }
  __syncthreads();
  for (int p = 15; p >= 0; --p){
    for (int idx = tid; idx < 4096; idx += 256)
      tile[idx >> 6][idx & 63] = DI[p * 4096 + idx];
    __syncthreads();
    {
      int c = tid & 63, q = tid >> 6;
      float s1 = 0.f, s2 = 0.f;
#pragma unroll
      for (int rr = 0; rr < 16; ++rr){
        int r = q * 16 + rr;
        float t = tile[r][c];
        s1 += t * z1[p * 64 + r];
        s2 += t * z2[p * 64 + r];
      }
      p1[q][c] = s1; p2[q][c] = s2;
    }
    __syncthreads();
    float n1 = 0.f, n2 = 0.f;
    if (tid < 64){
      n1 = p1[0][tid] + p1[1][tid] + p1[2][tid] + p1[3][tid];
      n2 = p2[0][tid] + p2[1][tid] + p2[2][tid] + p2[3][tid];
    }
    __syncthreads();
    if (tid < 64){ z1[p * 64 + tid] = n1; z2[p * 64 + tid] = n2; }
    __syncthreads();
    for (int cb = 0; cb < p; ++cb){
      for (int idx = tid; idx < 4096; idx += 256)
        tile[idx >> 6][idx & 63] = L[(size_t)(p * 64 + (idx >> 6)) * NPTS + cb * 64 + (idx & 63)];
      __syncthreads();
      int c = tid & 63, q = tid >> 6;
      float s1 = 0.f, s2 = 0.f;
#pragma unroll
      for (int rr = 0; rr < 16; ++rr){
        int r = q * 16 + rr;
        float t = tile[r][c];
        s1 += t * z1[p * 64 + r];
        s2 += t * z2[p * 64 + r];
      }
      p1[q][c] = s1; p2[q][c] = s2;
      __syncthreads();
      if (tid < 64){
        z1[cb * 64 + tid] -= p1[0][tid] + p1[1][tid] + p1[2][tid] + p1[3][tid];
        z2[cb * 64 + tid] -= p2[0][tid] + p2[1][tid] + p2[2][tid] + p2[3][tid];
      }
      __syncthreads();
    }
  }
  for (int i = tid; i < NPTS; i += 256)
    fbuf[(size_t)d * NPTS + i] = z1[NPTS - 1 - i] + z2[NPTS - 1 - i];
}

// ---------------- RNG kernels ----------------
__global__ __launch_bounds__(256) void k_gen_eps(u32 ka, u32 kb, float* eps){
  int i = blockIdx.x * 256 + threadIdx.x;
  if (i >= NDRAWS * NPTS) return;
  u32 bits = rand32(ka, kb, (u32)i, (u32)(NDRAWS * NPTS));
  eps[i] = normal_from_bits(bits);
}

__global__ __launch_bounds__(256) void k_init_f(const float* Lf, const float* eps, float* f){
  int d = blockIdx.y;
  int i = blockIdx.x * 256 + threadIdx.x;
  float s = 0.f;
  for (int j = 0; j <= i; ++j) s += Lf[(size_t)i * NPTS + j] * eps[(size_t)d * NPTS + j];
  f[(size_t)d * NPTS + i] = s;
}

__global__ __launch_bounds__(256) void k_pg(u32 ka, u32 kb, const float* f, float* omega){
  int idx = blockIdx.x * 256 + threadIdx.x;
  if (idx >= NDRAWS * NPTS) return;
  float c = f[idx];
  float c2w = (c * c) / 39.47841760435743f;
  float sum = 0.f;
  u32 base = (u32)idx * NG;
  for (int g = 0; g < NG; ++g){
    u32 bits = rand32(ka, kb, base + (u32)g, (u32)(NDRAWS * NPTS * NG));
    float u = u01f(bits);
    float e = -log1pf(-u);
    float kk = (float)g + 0.5f;
    sum += e / (kk * kk + c2w);
  }
  omega[idx] = sum / 19.739208802178716f;
}

// ---------------- final mll ----------------
__global__ __launch_bounds__(256) void k_build_Sz(const float* K, const float* omega, float* Ab, int c0){
  float* M = Ab + (size_t)blockIdx.y * NPTS * NPTS;
  int d = c0 + blockIdx.y;
  int idx = blockIdx.x * 256 + threadIdx.x;
  int i = idx >> 10, j = idx & 1023;
  float v = K[idx];
  if (i == j){
    float om = fmaxf(omega[(size_t)d * NPTS + i], 1e-16f);
    v += 1.0f / om + 1e-6f;
  }
  M[idx] = v;
}

__global__ __launch_bounds__(256) void k_final2(const float* Ab, const float* DinvF,
                                                const float* omega, const float* kappa,
                                                float* mll, int c0){
  int d0 = blockIdx.x, d = c0 + d0;
  const float* L = Ab + (size_t)d0 * NPTS * NPTS;
  const float* DI = DinvF + (size_t)d0 * 16 * 4096;
  __shared__ float z[NPTS];
  __shared__ float tile[64][65];
  __shared__ float part[4][64];
  __shared__ float red[4][4];
  int tid = threadIdx.x;
  float slo = 0.f, sko = 0.f;
  for (int i = tid; i < NPTS; i += 256){
    float om = fmaxf(omega[(size_t)d * NPTS + i], 1e-16f);
    float kj = kappa[i];
    z[i] = kj / om;
    slo += logf(om);
    sko += kj * kj / om;
  }
  __syncthreads();
  for (int p = 0; p < 16; ++p){
    for (int idx = tid; idx < 4096; idx += 256)
      tile[idx >> 6][idx & 63] = DI[p * 4096 + idx];
    __syncthreads();
    {
      int r = tid & 63, q = tid >> 6;
      float s = 0.f;
#pragma unroll
      for (int cc = 0; cc < 16; ++cc){
        int c = q * 16 + cc;
        s += tile[r][c] * z[p * 64 + c];
      }
      part[q][r] = s;
    }
    __syncthreads();
    float zn = 0.f;
    if (tid < 64) zn = part[0][tid] + part[1][tid] + part[2][tid] + part[3][tid];
    __syncthreads();
    if (tid < 64) z[p * 64 + tid] = zn;
    __syncthreads();
    for (int rb = p + 1; rb < 16; ++rb){
      for (int idx = tid; idx < 4096; idx += 256)
        tile[idx >> 6][idx & 63] = L[(size_t)(rb * 64 + (idx >> 6)) * NPTS + p * 64 + (idx & 63)];
      __syncthreads();
      int r = tid & 63, q = tid >> 6;
      float s = 0.f;
#pragma unroll
      for (int cc = 0; cc < 16; ++cc){
        int c = q * 16 + cc;
        s += tile[r][c] * z[p * 64 + c];
      }
      part[q][r] = s;
      __syncthreads();
      if (tid < 64) z[rb * 64 + tid] -= part[0][tid] + part[1][tid] + part[2][tid] + part[3][tid];
      __syncthreads();
    }
  }
  float q = 0.f, ld = 0.f;
  for (int i = tid; i < NPTS; i += 256){
    q += z[i] * z[i];
    ld += logf(L[(size_t)i * NPTS + i]);
  }
  int wid = tid >> 6, lane = tid & 63;
  for (int o = 32; o; o >>= 1){
    q += __shfl_down(q, o); ld += __shfl_down(ld, o);
    slo += __shfl_down(slo, o); sko += __shfl_down(sko, o);
  }
  if (lane == 0){ red[wid][0] = q; red[wid][1] = ld; red[wid][2] = slo; red[wid][3] = sko; }
  __syncthreads();
  if (tid == 0){
    q = 0.f; ld = 0.f; slo = 0.f; sko = 0.f;
    for (int w = 0; w < 4; ++w){ q += red[w][0]; ld += red[w][1]; slo += red[w][2]; sko += red[w][3]; }
    mll[d] = -0.5f * q - ld - 0.5f * slo + 0.5f * sko - 709.7827128933839f;
  }
}

__global__ void k_out(const float* mll, float* out){
  if (threadIdx.x == 0){
    float s = 0.f;
    for (int dd = 0; dd < NDRAWS; ++dd) s += mll[dd];
    float m = s / (float)NDRAWS;
    out[0] = (-m) / (float)NPTS;
  }
}

// ---------------- host-side key derivation ----------------
static void host_split(u32 ka, u32 kb, int num, u32* outA, u32* outB){
#if PARTITIONABLE
  for (int j = 0; j < num; ++j) tf2x32(ka, kb, 0u, (u32)j, &outA[j], &outB[j]);
#else
  u32 flat[40];
  for (int k = 0; k < num; ++k){
    u32 a, b; tf2x32(ka, kb, (u32)k, (u32)(num + k), &a, &b);
    flat[k] = a; flat[num + k] = b;
  }
  for (int j = 0; j < num; ++j){ outA[j] = flat[2 * j]; outB[j] = flat[2 * j + 1]; }
#endif
}

extern "C" void kernel_launch(void* const* d_in, const int* in_sizes, int n_in,
                              void* d_out, int out_size, void* d_ws, size_t ws_size,
                              hipStream_t stream){
  const float* X  = (const float*)d_in[0];
  const int*   Y  = (const int*)d_in[1];
  const float* osp = (const float*)d_in[2];
  const float* lsp = (const float*)d_in[3];
  float* out = (float*)d_out;

  const size_t NN = (size_t)NPTS * NPTS;
  char* p = (char*)d_ws;
  float*  K     = (float*)p;  p += NN * 4;
  float*  Lf    = (float*)p;  p += NN * 4;
  double* Ld    = (double*)p; p += NN * 8;
  double* Td    = (double*)p; p += NN * 8;
  double* DinvD = (double*)p; p += (size_t)16 * 4096 * 8;
  float*  Kinvf = (float*)p;  p += NN * 4;
  float*  omega = (float*)p;  p += (size_t)NDRAWS * NPTS * 4;
  float*  fbuf  = (float*)p;  p += (size_t)NDRAWS * NPTS * 4;
  float*  epsb  = (float*)p;  p += (size_t)NDRAWS * NPTS * 4;
  float*  kappa = (float*)p;  p += NPTS * 4;
  float*  kappaf= (float*)p;  p += NPTS * 4;
  float*  x2    = (float*)p;  p += NPTS * 4;
  float*  mll   = (float*)p;  p += NDRAWS * 4;
  uintptr_t ip = (uintptr_t)p; ip = (ip + 255) & ~(uintptr_t)255; p = (char*)ip;
  size_t used = (size_t)(p - (char*)d_ws);
  size_t rem = ws_size > used ? ws_size - used : 0;
  const size_t PER_DRAW = NN * 4 + (size_t)16 * 4096 * 4 + NPTS * 4 + 256;
  int CH = (int)(rem / PER_DRAW);
  if (CH > NDRAWS) CH = NDRAWS;
  if (CH < 1) CH = 1;
  float* bufA  = (float*)p;                    p += (size_t)CH * NN * 4;
  float* dinvF = (float*)p;                    p += (size_t)CH * 16 * 4096 * 4;
  float* zbuf  = (float*)p;

  // ---- keys (pure host arithmetic, identical every call) ----
  u32 r3A[3], r3B[3];
  host_split(0u, 42u, 3, r3A, r3B);
  u32 kiA = r3A[0], kiB = r3B[0];
  u32 koA = r3A[1], koB = r3B[1];
  u32 klA = r3A[2], klB = r3B[2];
  u32 kkA[NSTEPS], kkB[NSTEPS];
  host_split(klA, klB, NSTEPS, kkA, kkB);
  u32 k1A[NSTEPS], k1B[NSTEPS], k2A[NSTEPS], k2B[NSTEPS];
  for (int t = 0; t < NSTEPS; ++t){
    u32 sA[2], sB[2];
    host_split(kkA[t], kkB[t], 2, sA, sB);
    k1A[t] = sA[0]; k1B[t] = sB[0];
    k2A[t] = sA[1]; k2B[t] = sB[1];
  }

  // ---- setup: K, f64 chol, Lf, f64 trinv, flipped Kinv ----
  k_prep<<<dim3(4), 256, 0, stream>>>(X, Y, x2, kappa, kappaf);
  k_computeK<<<dim3(64, 64), dim3(16, 16), 0, stream>>>(X, x2, osp, lsp, K, Ld);
  run_chol<double>(Ld, DinvD, 1, stream);
  k_castL<<<dim3(4096), 256, 0, stream>>>(Ld, Lf);
  k_trinv_copy_diag<<<dim3(16), 256, 0, stream>>>(DinvD, Td);
  for (int lev = 1; lev < 16; ++lev)
    k_trinv_off_d<<<dim3(16 - lev), 256, 0, stream>>>(Ld, Td, lev);
  k_syrk_kinv_flip<<<dim3(256), 256, 0, stream>>>(Td, Kinvf);

  // ---- initial Gibbs state ----
  k_gen_eps<<<dim3(80), 256, 0, stream>>>(kiA, kiB, epsb);
  k_init_f<<<dim3(4, NDRAWS), 256, 0, stream>>>(Lf, epsb, fbuf);
  k_pg<<<dim3(80), 256, 0, stream>>>(koA, koB, fbuf, omega);

  // ---- Gibbs steps ----
  for (int t = 0; t < NSTEPS; ++t){
    k_gen_eps<<<dim3(80), 256, 0, stream>>>(k1A[t], k1B[t], epsb);
    for (int c0 = 0; c0 < NDRAWS; c0 += CH){
      int nb = NDRAWS - c0 < CH ? NDRAWS - c0 : CH;
      k_buildA<<<dim3(4096, nb), 256, 0, stream>>>(Kinvf, omega, bufA, c0);
      run_chol<float>(bufA, dinvF, nb, stream);
      k_fwd_solve<<<dim3(nb), 256, 0, stream>>>(bufA, dinvF, kappaf, zbuf);
      k_back_solve_f<<<dim3(nb), 256, 0, stream>>>(bufA, dinvF, zbuf, epsb, fbuf, c0);
    }
    k_pg<<<dim3(80), 256, 0, stream>>>(k2A[t], k2B[t], fbuf, omega);
  }

  // ---- final mll ----
  for (int c0 = 0; c0 < NDRAWS; c0 += CH){
    int nb = NDRAWS - c0 < CH ? NDRAWS - c0 : CH;
    k_build_Sz<<<dim3(4096, nb), 256, 0, stream>>>(K, omega, bufA, c0);
    run_chol<float>(bufA, dinvF, nb, stream);
    k_final2<<<dim3(nb), 256, 0, stream>>>(bufA, dinvF, omega, kappa, mll, c0);
  }
  k_out<<<dim3(1), 64, 0, stream>>>(mll, out);
}

// Round 3
// 33674.619 us; speedup vs baseline: 2.3498x; 1.0954x over previous
//
#include <hip/hip_runtime.h>
#include <stdint.h>

#define NPTS 1024
#define NDRAWS 20
#define NSTEPS 10
#define NG 100
#define PARTITIONABLE 1

typedef unsigned int u32;

// ---------------- threefry2x32 (JAX-compatible, 20 rounds) ----------------
__host__ __device__ static inline void tf2x32(u32 k0, u32 k1, u32 x0, u32 x1, u32* o0, u32* o1){
  u32 ks2 = k0 ^ k1 ^ 0x1BD11BDAu;
  x0 += k0; x1 += k1;
#define TFR(r) { x0 += x1; x1 = (x1 << r) | (x1 >> (32 - r)); x1 ^= x0; }
  TFR(13) TFR(15) TFR(26) TFR(6)
  x0 += k1; x1 += ks2 + 1u;
  TFR(17) TFR(29) TFR(16) TFR(24)
  x0 += ks2; x1 += k0 + 2u;
  TFR(13) TFR(15) TFR(26) TFR(6)
  x0 += k0; x1 += k1 + 3u;
  TFR(17) TFR(29) TFR(16) TFR(24)
  x0 += k1; x1 += ks2 + 4u;
  TFR(13) TFR(15) TFR(26) TFR(6)
  x0 += ks2; x1 += k0 + 5u;
#undef TFR
  *o0 = x0; *o1 = x1;
}

__device__ static inline u32 rand32(u32 ka, u32 kb, u32 i, u32 total){
  u32 a, b;
#if PARTITIONABLE
  (void)total;
  tf2x32(ka, kb, 0u, i, &a, &b);
  return a ^ b;
#else
  u32 h = total >> 1;
  if (i < h){ tf2x32(ka, kb, i, i + h, &a, &b); return a; }
  else      { tf2x32(ka, kb, i - h, i, &a, &b); return b; }
#endif
}

__device__ static inline float u01f(u32 bits){
  return __uint_as_float(0x3F800000u | (bits >> 9)) - 1.0f;
}

// XLA ErfInv32 (Giles) polynomial
__device__ static inline float erfinv32(float x){
  float w = -log1pf(-x * x);
  float p;
  if (w < 5.0f){
    w -= 2.5f;
    p = 2.81022636e-08f;
    p = fmaf(p, w, 3.43273939e-07f);
    p = fmaf(p, w, -3.5233877e-06f);
    p = fmaf(p, w, -4.39150654e-06f);
    p = fmaf(p, w, 0.00021858087f);
    p = fmaf(p, w, -0.00125372503f);
    p = fmaf(p, w, -0.00417768164f);
    p = fmaf(p, w, 0.246640727f);
    p = fmaf(p, w, 1.50140941f);
  } else {
    w = sqrtf(w) - 3.0f;
    p = -0.000200214257f;
    p = fmaf(p, w, 0.000100950558f);
    p = fmaf(p, w, 0.00134934322f);
    p = fmaf(p, w, -0.00367342844f);
    p = fmaf(p, w, 0.00573950773f);
    p = fmaf(p, w, -0.0076224613f);
    p = fmaf(p, w, 0.00943887047f);
    p = fmaf(p, w, 1.00167406f);
    p = fmaf(p, w, 2.83297682f);
  }
  return p * x;
}

__device__ static inline float normal_from_bits(u32 bits){
  const float LO = -0.99999994f;
  float u = u01f(bits);
  float v = u * 2.0f + LO;
  v = fmaxf(LO, v);
  return 1.4142135623730951f * erfinv32(v);
}

__device__ inline float  tsqrt(float x){ return sqrtf(x); }
__device__ inline double tsqrt(double x){ return sqrt(x); }
__device__ inline float  tmax(float a, float b){ return fmaxf(a, b); }
__device__ inline double tmax(double a, double b){ return fmax(a, b); }

__device__ inline void tri_decode(int p, int& ti, int& tj){
  int t = (int)((sqrtf(8.0f * (float)p + 1.0f) - 1.0f) * 0.5f);
  while ((t + 1) * (t + 2) / 2 <= p) ++t;
  while (t * (t + 1) / 2 > p) --t;
  ti = t; tj = p - t * (t + 1) / 2;
}

// ---------------- setup kernels ----------------
__global__ __launch_bounds__(256) void k_prep(const float* X, const int* Y, float* x2, float* kappaf){
  int n = blockIdx.x * 256 + threadIdx.x;
  if (n >= NPTS) return;
  float s = 0.f;
  for (int d = 0; d < 64; ++d){ float v = X[n * 64 + d]; s += v * v; }
  x2[n] = s;
  kappaf[NPTS - 1 - n] = (float)Y[n] - 0.5f;
}

__global__ void k_computeK(const float* X, const float* x2, const float* osp, const float* lsp,
                           double* Ld){
  int j = blockIdx.x * 16 + threadIdx.x;
  int i = blockIdx.y * 16 + threadIdx.y;
  float os = osp[0], ls = lsp[0];
  float dot = 0.f;
  for (int d = 0; d < 64; ++d) dot += X[i * 64 + d] * X[j * 64 + d];
  float d2 = x2[i] + x2[j] - 2.0f * dot;
  d2 = fmaxf(d2, 0.0f);
  float kv = os * expf((-0.5f * d2) / (ls * ls));
  Ld[(size_t)i * NPTS + j] = (double)kv + (i == j ? 1e-6 : 0.0);
}

__global__ __launch_bounds__(256) void k_castL(const double* Ld, float* Lf){
  int idx = blockIdx.x * 256 + threadIdx.x;
  int i = idx >> 10, j = idx & 1023;
  Lf[idx] = (j <= i) ? (float)Ld[idx] : 0.0f;
}

__global__ __launch_bounds__(256) void k_logdetK(const double* Ld, float* ldetK){
  __shared__ double red[4];
  int tid = threadIdx.x;
  double s = 0.0;
  for (int i = tid; i < NPTS; i += 256) s += log(Ld[(size_t)i * NPTS + i]);
  for (int o = 32; o; o >>= 1) s += __shfl_down(s, o);
  if ((tid & 63) == 0) red[tid >> 6] = s;
  __syncthreads();
  if (tid == 0) ldetK[0] = (float)(2.0 * (red[0] + red[1] + red[2] + red[3]));
}

// ---------------- f64 blocked Cholesky (setup only) ----------------
template<typename T>
__global__ __launch_bounds__(256) void k_chol_diag_inv(T* A, T* Dinv, int p){
  T* M = A + (size_t)blockIdx.x * NPTS * NPTS;
  T* DI = Dinv + ((size_t)blockIdx.x * 16 + p) * 4096;
  int k0 = p * 64;
  __shared__ T t[64][65];
  __shared__ T Xs[64][65];
  int tid = threadIdx.x;
  for (int idx = tid; idx < 4096; idx += 256){
    int r = idx >> 6, c = idx & 63;
    t[r][c] = (c <= r) ? M[(size_t)(k0 + r) * NPTS + k0 + c] : (T)0;
    Xs[r][c] = (T)0;
  }
  __syncthreads();
  for (int j = 0; j < 64; ++j){
    T piv = tsqrt(tmax(t[j][j], (T)1e-30));
    T inv = (T)1 / piv;
    __syncthreads();
    if (tid == 0) t[j][j] = piv;
    for (int r = j + 1 + tid; r < 64; r += 256) t[r][j] *= inv;
    __syncthreads();
    int tr = tid & 63, tg = tid >> 6;
    for (int r = j + 1 + tg; r < 64; r += 4){
      int c = j + 1 + tr;
      if (c <= r) t[r][c] -= t[r][j] * t[c][j];
    }
    __syncthreads();
  }
  for (int idx = tid; idx < 4096; idx += 256){
    int r = idx >> 6, c = idx & 63;
    M[(size_t)(k0 + r) * NPTS + k0 + c] = (c <= r) ? t[r][c] : (T)0;
  }
  if (tid < 64){
    int c = tid;
    Xs[c][c] = (T)1 / t[c][c];
    for (int r = c + 1; r < 64; ++r){
      T s = (T)0;
      for (int k = c; k < r; ++k) s += t[r][k] * Xs[k][c];
      Xs[r][c] = -s / t[r][r];
    }
  }
  __syncthreads();
  for (int idx = tid; idx < 4096; idx += 256){
    int r = idx >> 6, c = idx & 63;
    DI[idx] = Xs[r][c];
  }
}

// ---------------- f32 wave-lockstep diag chol + inverse ----------------
__global__ __launch_bounds__(64) void k_chol_diag_wave(float* A, float* Dinv, int p){
  float* M = A + (size_t)blockIdx.x * NPTS * NPTS;
  float* DI = Dinv + ((size_t)blockIdx.x * 16 + p) * 4096;
  const int k0 = p * 64;
  int lane = threadIdx.x;
  __shared__ float lds[64 * 65];
  for (int i = 0; i < 64; ++i) lds[i * 65 + lane] = M[(size_t)(k0 + i) * NPTS + k0 + lane];
  __syncthreads();
  float row[64];
#pragma unroll
  for (int c = 0; c < 64; ++c) row[c] = lds[lane * 65 + c];
  // right-looking Cholesky, wave-lockstep, fully unrolled
#pragma unroll
  for (int j = 0; j < 64; ++j){
    float tjj = __shfl(row[j], j);
    float piv = sqrtf(fmaxf(tjj, 1e-30f));
    float inv = 1.0f / piv;
    if (lane > j) row[j] *= inv;
    else if (lane == j) row[j] = piv;
#pragma unroll
    for (int c = j + 1; c < 64; ++c){
      float tcj = __shfl(row[j], c);     // t[c][j] (scaled, lane c)
      row[c] = fmaf(-row[j], tcj, row[c]);
    }
  }
  // write back L (lower, zeros upper)
#pragma unroll
  for (int c = 0; c < 64; ++c) lds[lane * 65 + c] = (c <= lane) ? row[c] : 0.0f;
  __syncthreads();
  for (int i = 0; i < 64; ++i) M[(size_t)(k0 + i) * NPTS + k0 + lane] = lds[i * 65 + lane];
  // triangular inverse: lane owns column 'lane', X in registers
  float X[64];
#pragma unroll
  for (int r = 0; r < 64; ++r){
    float acc = 0.f;
#pragma unroll
    for (int k = 0; k < 64; ++k){
      if (k < r) acc = fmaf(__shfl(row[k], r), X[k], acc);
    }
    float diag = __shfl(row[r], r);
    X[r] = ((lane == r ? 1.0f : 0.0f) - acc) / diag;
  }
  __syncthreads();
#pragma unroll
  for (int r = 0; r < 64; ++r) lds[r * 65 + lane] = X[r];
  __syncthreads();
  for (int i = 0; i < 64; ++i) DI[i * 64 + lane] = lds[i * 65 + lane];
}

// Panel: R <- R * Dinv^T
template<typename T>
__global__ __launch_bounds__(256) void k_chol_panel_gemm(T* A, const T* Dinv, int p){
  T* M = A + (size_t)blockIdx.y * NPTS * NPTS;
  const T* DI = Dinv + ((size_t)blockIdx.y * 16 + p) * 4096;
  int r0 = (p + 1) * 64 + blockIdx.x * 64;
  __shared__ T Rs[64][65];
  __shared__ T Ds[64][65];
  int tid = threadIdx.x;
  for (int idx = tid; idx < 4096; idx += 256){
    int r = idx >> 6, c = idx & 63;
    Rs[r][c] = M[(size_t)(r0 + r) * NPTS + p * 64 + c];
    Ds[r][c] = DI[idx];
  }
  __syncthreads();
  int tx = tid & 15, ty = tid >> 4;
  T acc[4][4];
#pragma unroll
  for (int a = 0; a < 4; ++a)
#pragma unroll
    for (int b = 0; b < 4; ++b) acc[a][b] = (T)0;
  for (int k = 0; k < 64; ++k){
    T av[4], bv[4];
#pragma unroll
    for (int a = 0; a < 4; ++a) av[a] = Rs[ty * 4 + a][k];
#pragma unroll
    for (int b = 0; b < 4; ++b) bv[b] = Ds[tx * 4 + b][k];
#pragma unroll
    for (int a = 0; a < 4; ++a)
#pragma unroll
      for (int b = 0; b < 4; ++b) acc[a][b] += av[a] * bv[b];
  }
#pragma unroll
  for (int a = 0; a < 4; ++a)
#pragma unroll
    for (int b = 0; b < 4; ++b)
      M[(size_t)(r0 + ty * 4 + a) * NPTS + p * 64 + tx * 4 + b] = acc[a][b];
}

// Trailing update
template<typename T>
__global__ __launch_bounds__(256) void k_chol_update(T* A, int k0){
  T* M = A + (size_t)blockIdx.y * NPTS * NPTS;
  __shared__ T Pa[64][65];
  __shared__ T Pb[64][65];
  int ti, tj; tri_decode(blockIdx.x, ti, tj);
  int bi = k0 + 64 + ti * 64;
  int bj = k0 + 64 + tj * 64;
  int tid = threadIdx.x;
  for (int idx = tid; idx < 4096; idx += 256){
    int r = idx >> 6, c = idx & 63;
    Pa[r][c] = M[(size_t)(bi + r) * NPTS + k0 + c];
    Pb[r][c] = M[(size_t)(bj + r) * NPTS + k0 + c];
  }
  __syncthreads();
  int tx = tid & 15, ty = tid >> 4;
  T acc[4][4];
#pragma unroll
  for (int a = 0; a < 4; ++a)
#pragma unroll
    for (int b = 0; b < 4; ++b) acc[a][b] = (T)0;
  for (int k = 0; k < 64; ++k){
    T av[4], bv[4];
#pragma unroll
    for (int a = 0; a < 4; ++a) av[a] = Pa[ty * 4 + a][k];
#pragma unroll
    for (int b = 0; b < 4; ++b) bv[b] = Pb[tx * 4 + b][k];
#pragma unroll
    for (int a = 0; a < 4; ++a)
#pragma unroll
      for (int b = 0; b < 4; ++b) acc[a][b] += av[a] * bv[b];
  }
#pragma unroll
  for (int a = 0; a < 4; ++a)
#pragma unroll
    for (int b = 0; b < 4; ++b){
      int gi = bi + ty * 4 + a, gj = bj + tx * 4 + b;
      M[(size_t)gi * NPTS + gj] -= acc[a][b];
    }
}

static void run_chol_d(double* A, double* Dinv, hipStream_t s){
  for (int p = 0; p < 16; ++p){
    k_chol_diag_inv<double><<<dim3(1), 256, 0, s>>>(A, Dinv, p);
    int nrb = 15 - p;
    if (nrb > 0){
      k_chol_panel_gemm<double><<<dim3(nrb, 1), 256, 0, s>>>(A, Dinv, p);
      k_chol_update<double><<<dim3(nrb * (nrb + 1) / 2, 1), 256, 0, s>>>(A, p * 64);
    }
  }
}

static void run_chol_f(float* A, float* Dinv, int batch, hipStream_t s){
  for (int p = 0; p < 16; ++p){
    k_chol_diag_wave<<<dim3(batch), 64, 0, s>>>(A, Dinv, p);
    int nrb = 15 - p;
    if (nrb > 0){
      k_chol_panel_gemm<float><<<dim3(nrb, batch), 256, 0, s>>>(A, Dinv, p);
      k_chol_update<float><<<dim3(nrb * (nrb + 1) / 2, batch), 256, 0, s>>>(A, p * 64);
    }
  }
}

// ---------------- f64 triangular inverse (one-time, for Kinv) ----------------
__global__ __launch_bounds__(256) void k_trinv_copy_diag(const double* DinvD, double* Td){
  int p = blockIdx.x;
  for (int idx = threadIdx.x; idx < 4096; idx += 256){
    int r = idx >> 6, c = idx & 63;
    Td[(size_t)(p * 64 + r) * NPTS + p * 64 + c] = DinvD[(size_t)p * 4096 + idx];
  }
}

__global__ __launch_bounds__(256) void k_trinv_off_d(const double* Lm, double* Li, int lev){
  const double* M = Lm;
  double* O = Li;
  int J = blockIdx.x, I = J + lev;
  __shared__ double Ta[64][65];
  __shared__ double Tb[64][65];
  int tid = threadIdx.x, tx = tid & 15, ty = tid >> 4;
  double acc[4][4];
#pragma unroll
  for (int a = 0; a < 4; ++a)
#pragma unroll
    for (int b = 0; b < 4; ++b) acc[a][b] = 0.0;
  for (int K = J; K < I; ++K){
    __syncthreads();
    for (int idx = tid; idx < 4096; idx += 256){
      int r = idx >> 6, c = idx & 63;
      Ta[r][c] = M[(size_t)(I * 64 + r) * NPTS + K * 64 + c];
      Tb[r][c] = O[(size_t)(K * 64 + r) * NPTS + J * 64 + c];
    }
    __syncthreads();
    for (int k = 0; k < 64; ++k){
      double av[4], bv[4];
#pragma unroll
      for (int a = 0; a < 4; ++a) av[a] = Ta[ty * 4 + a][k];
#pragma unroll
      for (int b = 0; b < 4; ++b) bv[b] = Tb[k][tx * 4 + b];
#pragma unroll
      for (int a = 0; a < 4; ++a)
#pragma unroll
        for (int b = 0; b < 4; ++b) acc[a][b] += av[a] * bv[b];
    }
  }
  __syncthreads();
#pragma unroll
  for (int a = 0; a < 4; ++a)
#pragma unroll
    for (int b = 0; b < 4; ++b) Tb[ty * 4 + a][tx * 4 + b] = acc[a][b];
  for (int idx = tid; idx < 4096; idx += 256){
    int r = idx >> 6, c = idx & 63;
    Ta[r][c] = O[(size_t)(I * 64 + r) * NPTS + I * 64 + c];
  }
  __syncthreads();
  double ac2[4][4];
#pragma unroll
  for (int a = 0; a < 4; ++a)
#pragma unroll
    for (int b = 0; b < 4; ++b) ac2[a][b] = 0.0;
  for (int k = 0; k < 64; ++k){
    double av[4], bv[4];
#pragma unroll
    for (int a = 0; a < 4; ++a) av[a] = Ta[ty * 4 + a][k];
#pragma unroll
    for (int b = 0; b < 4; ++b) bv[b] = Tb[k][tx * 4 + b];
#pragma unroll
    for (int a = 0; a < 4; ++a)
#pragma unroll
      for (int b = 0; b < 4; ++b) ac2[a][b] += av[a] * bv[b];
  }
#pragma unroll
  for (int a = 0; a < 4; ++a)
#pragma unroll
    for (int b = 0; b < 4; ++b)
      O[(size_t)(I * 64 + ty * 4 + a) * NPTS + J * 64 + tx * 4 + b] = -ac2[a][b];
}

// Kinvf[i][j] = (float)(Td^T Td)[1023-i][1023-j]
__global__ __launch_bounds__(256) void k_syrk_kinv_flip(const double* Td, float* Kinvf){
  int ti = blockIdx.x >> 4, tj = blockIdx.x & 15;
  int kmin = ti > tj ? ti : tj;
  __shared__ double Ta[64][65];
  __shared__ double Tb[64][65];
  int tid = threadIdx.x, tx = tid & 15, ty = tid >> 4;
  double acc[4][4];
#pragma unroll
  for (int a = 0; a < 4; ++a)
#pragma unroll
    for (int b = 0; b < 4; ++b) acc[a][b] = 0.0;
  for (int K = kmin; K < 16; ++K){
    __syncthreads();
    for (int idx = tid; idx < 4096; idx += 256){
      int r = idx >> 6, c = idx & 63;
      Ta[r][c] = Td[(size_t)(K * 64 + r) * NPTS + ti * 64 + c];
      Tb[r][c] = Td[(size_t)(K * 64 + r) * NPTS + tj * 64 + c];
    }
    __syncthreads();
    for (int k = 0; k < 64; ++k){
      double av[4], bv[4];
#pragma unroll
      for (int a = 0; a < 4; ++a) av[a] = Ta[k][ty * 4 + a];
#pragma unroll
      for (int b = 0; b < 4; ++b) bv[b] = Tb[k][tx * 4 + b];
#pragma unroll
      for (int a = 0; a < 4; ++a)
#pragma unroll
        for (int b = 0; b < 4; ++b) acc[a][b] += av[a] * bv[b];
    }
  }
#pragma unroll
  for (int a = 0; a < 4; ++a)
#pragma unroll
    for (int b = 0; b < 4; ++b){
      int gi = ti * 64 + ty * 4 + a, gj = tj * 64 + tx * 4 + b;
      Kinvf[(size_t)(NPTS - 1 - gi) * NPTS + (NPTS - 1 - gj)] = (float)acc[a][b];
    }
}

// ---------------- per-step kernels ----------------
__global__ __launch_bounds__(256) void k_buildA(const float* Kinvf, const float* omega, float* Ab,
                                                int c0, int clip){
  int d = c0 + blockIdx.y;
  float* A = Ab + (size_t)blockIdx.y * NPTS * NPTS;
  int idx4 = blockIdx.x * 256 + threadIdx.x;   // grid.x = 1024
  float4 v = ((const float4*)Kinvf)[idx4];
  int e = idx4 * 4;
  int i = e >> 10, j0 = e & 1023;
  if (j0 <= i && i < j0 + 4){
    float om = omega[(size_t)d * NPTS + (NPTS - 1 - i)];
    if (clip) om = fmaxf(om, 1e-16f);
    ((float*)&v)[i - j0] += om;
  }
  ((float4*)A)[idx4] = v;
}

// forward solve (double-buffered): Lb z = kappaf
__global__ __launch_bounds__(256) void k_fwd_solve(const float* Ab, const float* DinvF,
                                                   const float* kappaf, float* zbuf){
  int d0 = blockIdx.x;
  const float* L = Ab + (size_t)d0 * NPTS * NPTS;
  const float* DI = DinvF + (size_t)d0 * 16 * 4096;
  __shared__ float z[NPTS];
  __shared__ float buf[2][64 * 65];
  __shared__ float part[4][64];
  int tid = threadIdx.x;
  float4 rg[4];
  auto loadDI = [&](int p){
#pragma unroll
    for (int j = 0; j < 4; ++j)
      rg[j] = *(const float4*)&DI[p * 4096 + j * 1024 + tid * 4];
  };
  auto loadL = [&](int rbrow, int pcol){
#pragma unroll
    for (int j = 0; j < 4; ++j){
      int e = j * 1024 + tid * 4; int r = e >> 6, c = e & 63;
      rg[j] = *(const float4*)&L[(size_t)(rbrow * 64 + r) * NPTS + pcol * 64 + c];
    }
  };
  auto store = [&](int cur){
#pragma unroll
    for (int j = 0; j < 4; ++j){
      int e = j * 1024 + tid * 4; int r = e >> 6, c = e & 63;
      float* b = &buf[cur][r * 65 + c];
      b[0] = rg[j].x; b[1] = rg[j].y; b[2] = rg[j].z; b[3] = rg[j].w;
    }
  };
  for (int i = tid; i < NPTS; i += 256) z[i] = kappaf[i];
  loadDI(0);
  int cur = 0;
  for (int p = 0; p < 16; ++p){
    for (int rb = p; rb < 16; ++rb){
      store(cur);
      int np = p, nrb = rb + 1;
      if (nrb >= 16){ np = p + 1; nrb = np; }
      if (np < 16){ if (nrb == np) loadDI(np); else loadL(nrb, np); }
      __syncthreads();
      int rr = tid & 63, q = tid >> 6;
      float s = 0.f;
#pragma unroll
      for (int cc = 0; cc < 16; ++cc)
        s += buf[cur][rr * 65 + q * 16 + cc] * z[p * 64 + q * 16 + cc];
      part[q][rr] = s;
      __syncthreads();
      if (tid < 64){
        float v = part[0][tid] + part[1][tid] + part[2][tid] + part[3][tid];
        if (rb == p) z[p * 64 + tid] = v;
        else z[rb * 64 + tid] -= v;
      }
      __syncthreads();
      cur ^= 1;
    }
  }
  for (int i = tid; i < NPTS; i += 256) zbuf[(size_t)d0 * NPTS + i] = z[i];
}

// back solve (double-buffered, 2 RHS): y1 = Lb^-T z ; y2 = Lb^-T (P eps); f = P(y1+y2)
__global__ __launch_bounds__(256) void k_back_solve_f(const float* Ab, const float* DinvF,
                                                      const float* zbuf, const float* eps,
                                                      float* fbuf, int c0){
  int d0 = blockIdx.x, d = c0 + d0;
  const float* L = Ab + (size_t)d0 * NPTS * NPTS;
  const float* DI = DinvF + (size_t)d0 * 16 * 4096;
  __shared__ float z1[NPTS], z2[NPTS];
  __shared__ float buf[2][64 * 65];
  __shared__ float p1[4][64], p2[4][64];
  int tid = threadIdx.x;
  float4 rg[4];
  auto loadDI = [&](int p){
#pragma unroll
    for (int j = 0; j < 4; ++j)
      rg[j] = *(const float4*)&DI[p * 4096 + j * 1024 + tid * 4];
  };
  auto loadL = [&](int prow, int cbcol){
#pragma unroll
    for (int j = 0; j < 4; ++j){
      int e = j * 1024 + tid * 4; int r = e >> 6, c = e & 63;
      rg[j] = *(const float4*)&L[(size_t)(prow * 64 + r) * NPTS + cbcol * 64 + c];
    }
  };
  auto store = [&](int cur){
#pragma unroll
    for (int j = 0; j < 4; ++j){
      int e = j * 1024 + tid * 4; int r = e >> 6, c = e & 63;
      float* b = &buf[cur][r * 65 + c];
      b[0] = rg[j].x; b[1] = rg[j].y; b[2] = rg[j].z; b[3] = rg[j].w;
    }
  };
  for (int i = tid; i < NPTS; i += 256){
    z1[i] = zbuf[(size_t)d0 * NPTS + i];
    z2[NPTS - 1 - i] = eps[(size_t)d * NPTS + i];
  }
  loadDI(15);
  int cur = 0;
  for (int p = 15; p >= 0; --p){
    for (int cb = p; cb >= 0; --cb){
      store(cur);
      int np = p, ncb = cb - 1;
      if (ncb < 0){ np = p - 1; ncb = np; }
      if (np >= 0){ if (ncb == np) loadDI(np); else loadL(np, ncb); }
      __syncthreads();
      int cc = tid & 63, q = tid >> 6;
      float s1 = 0.f, s2 = 0.f;
#pragma unroll
      for (int rr = 0; rr < 16; ++rr){
        float t = buf[cur][(q * 16 + rr) * 65 + cc];
        s1 += t * z1[p * 64 + q * 16 + rr];
        s2 += t * z2[p * 64 + q * 16 + rr];
      }
      p1[q][cc] = s1; p2[q][cc] = s2;
      __syncthreads();
      if (tid < 64){
        float v1 = p1[0][tid] + p1[1][tid] + p1[2][tid] + p1[3][tid];
        float v2 = p2[0][tid] + p2[1][tid] + p2[2][tid] + p2[3][tid];
        if (cb == p){ z1[p * 64 + tid] = v1; z2[p * 64 + tid] = v2; }
        else { z1[cb * 64 + tid] -= v1; z2[cb * 64 + tid] -= v2; }
      }
      __syncthreads();
      cur ^= 1;
    }
  }
  for (int i = tid; i < NPTS; i += 256)
    fbuf[(size_t)d * NPTS + i] = z1[NPTS - 1 - i] + z2[NPTS - 1 - i];
}

// fused final: solve Lb z = kappaf, mll = 0.5*||z||^2 + sum log diag(DI) - 0.5*ldetK - N log2
__global__ __launch_bounds__(256) void k_final3(const float* Ab, const float* DinvF,
                                                const float* kappaf, const float* ldetK,
                                                float* mll, int c0){
  int d0 = blockIdx.x, d = c0 + d0;
  const float* L = Ab + (size_t)d0 * NPTS * NPTS;
  const float* DI = DinvF + (size_t)d0 * 16 * 4096;
  __shared__ float z[NPTS];
  __shared__ float buf[2][64 * 65];
  __shared__ float part[4][64];
  __shared__ float redq[4];
  int tid = threadIdx.x;
  float4 rg[4];
  auto loadDI = [&](int p){
#pragma unroll
    for (int j = 0; j < 4; ++j)
      rg[j] = *(const float4*)&DI[p * 4096 + j * 1024 + tid * 4];
  };
  auto loadL = [&](int rbrow, int pcol){
#pragma unroll
    for (int j = 0; j < 4; ++j){
      int e = j * 1024 + tid * 4; int r = e >> 6, c = e & 63;
      rg[j] = *(const float4*)&L[(size_t)(rbrow * 64 + r) * NPTS + pcol * 64 + c];
    }
  };
  auto store = [&](int cur){
#pragma unroll
    for (int j = 0; j < 4; ++j){
      int e = j * 1024 + tid * 4; int r = e >> 6, c = e & 63;
      float* b = &buf[cur][r * 65 + c];
      b[0] = rg[j].x; b[1] = rg[j].y; b[2] = rg[j].z; b[3] = rg[j].w;
    }
  };
  for (int i = tid; i < NPTS; i += 256) z[i] = kappaf[i];
  loadDI(0);
  int cur = 0;
  float ldacc = 0.f;
  for (int p = 0; p < 16; ++p){
    for (int rb = p; rb < 16; ++rb){
      store(cur);
      int np = p, nrb = rb + 1;
      if (nrb >= 16){ np = p + 1; nrb = np; }
      if (np < 16){ if (nrb == np) loadDI(np); else loadL(nrb, np); }
      __syncthreads();
      if (rb == p && tid < 64) ldacc += logf(buf[cur][tid * 65 + tid]);
      int rr = tid & 63, q = tid >> 6;
      float s = 0.f;
#pragma unroll
      for (int cc = 0; cc < 16; ++cc)
        s += buf[cur][rr * 65 + q * 16 + cc] * z[p * 64 + q * 16 + cc];
      part[q][rr] = s;
      __syncthreads();
      if (tid < 64){
        float v = part[0][tid] + part[1][tid] + part[2][tid] + part[3][tid];
        if (rb == p) z[p * 64 + tid] = v;
        else z[rb * 64 + tid] -= v;
      }
      __syncthreads();
      cur ^= 1;
    }
  }
  float q2 = 0.f;
  for (int i = tid; i < NPTS; i += 256) q2 += z[i] * z[i];
  int wid = tid >> 6, lane = tid & 63;
  for (int o = 32; o; o >>= 1) q2 += __shfl_down(q2, o);
  if (lane == 0) redq[wid] = q2;
  __syncthreads();
  if (tid < 64){
    float ldv = ldacc;
    for (int o = 32; o; o >>= 1) ldv += __shfl_down(ldv, o);
    if (tid == 0){
      float q2t = redq[0] + redq[1] + redq[2] + redq[3];
      mll[d] = 0.5f * q2t + ldv - 0.5f * ldetK[0] - 709.7827128933839f;
    }
  }
}

// ---------------- RNG kernels ----------------
__global__ __launch_bounds__(256) void k_gen_eps(u32 ka, u32 kb, float* eps){
  int i = blockIdx.x * 256 + threadIdx.x;
  if (i >= NDRAWS * NPTS) return;
  u32 bits = rand32(ka, kb, (u32)i, (u32)(NDRAWS * NPTS));
  eps[i] = normal_from_bits(bits);
}

// tiled f = Lf * eps (lower-tri matvec per draw)
__global__ __launch_bounds__(256) void k_init_f2(const float* Lf, const float* eps, float* f){
  int d = blockIdx.y, rb = blockIdx.x;
  __shared__ float tile[64][65];
  __shared__ float ev[64];
  __shared__ float part[4][64];
  int tid = threadIdx.x;
  int r = tid & 63, q = tid >> 6;
  float acc = 0.f;
  for (int kt = 0; kt <= rb; ++kt){
    __syncthreads();
#pragma unroll
    for (int j = 0; j < 4; ++j){
      int e = j * 1024 + tid * 4; int rr = e >> 6, cc = e & 63;
      float4 v = *(const float4*)&Lf[(size_t)(rb * 64 + rr) * NPTS + kt * 64 + cc];
      tile[rr][cc] = v.x; tile[rr][cc + 1] = v.y; tile[rr][cc + 2] = v.z; tile[rr][cc + 3] = v.w;
    }
    if (tid < 64) ev[tid] = eps[(size_t)d * NPTS + kt * 64 + tid];
    __syncthreads();
    int cmax = (kt == rb) ? (r + 1) : 64;
    for (int cc = q * 16; cc < q * 16 + 16; ++cc){
      if (cc < cmax) acc += tile[r][cc] * ev[cc];
    }
  }
  part[q][r] = acc;
  __syncthreads();
  if (tid < 64){
    float s = part[0][tid] + part[1][tid] + part[2][tid] + part[3][tid];
    f[(size_t)d * NPTS + rb * 64 + tid] = s;
  }
}

__global__ __launch_bounds__(256) void k_pg(u32 ka, u32 kb, const float* f, float* omega){
  int idx = blockIdx.x * 256 + threadIdx.x;
  if (idx >= NDRAWS * NPTS) return;
  float c = f[idx];
  float c2w = (c * c) / 39.47841760435743f;
  float sum = 0.f;
  u32 base = (u32)idx * NG;
  for (int g = 0; g < NG; ++g){
    u32 bits = rand32(ka, kb, base + (u32)g, (u32)(NDRAWS * NPTS * NG));
    float u = u01f(bits);
    float e = -log1pf(-u);
    float kk = (float)g + 0.5f;
    sum += e / (kk * kk + c2w);
  }
  omega[idx] = sum / 19.739208802178716f;
}

__global__ void k_out(const float* mll, float* out){
  if (threadIdx.x == 0){
    float s = 0.f;
    for (int dd = 0; dd < NDRAWS; ++dd) s += mll[dd];
    float m = s / (float)NDRAWS;
    out[0] = (-m) / (float)NPTS;
  }
}

// ---------------- host-side key derivation ----------------
static void host_split(u32 ka, u32 kb, int num, u32* outA, u32* outB){
#if PARTITIONABLE
  for (int j = 0; j < num; ++j) tf2x32(ka, kb, 0u, (u32)j, &outA[j], &outB[j]);
#else
  u32 flat[40];
  for (int k = 0; k < num; ++k){
    u32 a, b; tf2x32(ka, kb, (u32)k, (u32)(num + k), &a, &b);
    flat[k] = a; flat[num + k] = b;
  }
  for (int j = 0; j < num; ++j){ outA[j] = flat[2 * j]; outB[j] = flat[2 * j + 1]; }
#endif
}

extern "C" void kernel_launch(void* const* d_in, const int* in_sizes, int n_in,
                              void* d_out, int out_size, void* d_ws, size_t ws_size,
                              hipStream_t stream){
  const float* X  = (const float*)d_in[0];
  const int*   Y  = (const int*)d_in[1];
  const float* osp = (const float*)d_in[2];
  const float* lsp = (const float*)d_in[3];
  float* out = (float*)d_out;

  const size_t NN = (size_t)NPTS * NPTS;
  char* p = (char*)d_ws;
  float*  Lf    = (float*)p;  p += NN * 4;
  double* Ld    = (double*)p; p += NN * 8;
  double* Td    = (double*)p; p += NN * 8;
  double* DinvD = (double*)p; p += (size_t)16 * 4096 * 8;
  float*  Kinvf = (float*)p;  p += NN * 4;
  float*  omega = (float*)p;  p += (size_t)NDRAWS * NPTS * 4;
  float*  fbuf  = (float*)p;  p += (size_t)NDRAWS * NPTS * 4;
  float*  epsb  = (float*)p;  p += (size_t)NDRAWS * NPTS * 4;
  float*  kappaf= (float*)p;  p += NPTS * 4;
  float*  x2    = (float*)p;  p += NPTS * 4;
  float*  mll   = (float*)p;  p += NDRAWS * 4;
  float*  ldetK = (float*)p;  p += 256;
  uintptr_t ip = (uintptr_t)p; ip = (ip + 255) & ~(uintptr_t)255; p = (char*)ip;
  size_t used = (size_t)(p - (char*)d_ws);
  size_t rem = ws_size > used ? ws_size - used : 0;
  const size_t PER_DRAW = NN * 4 + (size_t)16 * 4096 * 4 + NPTS * 4 + 256;
  int CH = (int)(rem / PER_DRAW);
  if (CH > NDRAWS) CH = NDRAWS;
  if (CH < 1) CH = 1;
  float* bufA  = (float*)p;                    p += (size_t)CH * NN * 4;
  float* dinvF = (float*)p;                    p += (size_t)CH * 16 * 4096 * 4;
  float* zbuf  = (float*)p;

  // ---- keys ----
  u32 r3A[3], r3B[3];
  host_split(0u, 42u, 3, r3A, r3B);
  u32 kiA = r3A[0], kiB = r3B[0];
  u32 koA = r3A[1], koB = r3B[1];
  u32 klA = r3A[2], klB = r3B[2];
  u32 kkA[NSTEPS], kkB[NSTEPS];
  host_split(klA, klB, NSTEPS, kkA, kkB);
  u32 k1A[NSTEPS], k1B[NSTEPS], k2A[NSTEPS], k2B[NSTEPS];
  for (int t = 0; t < NSTEPS; ++t){
    u32 sA[2], sB[2];
    host_split(kkA[t], kkB[t], 2, sA, sB);
    k1A[t] = sA[0]; k1B[t] = sB[0];
    k2A[t] = sA[1]; k2B[t] = sB[1];
  }

  // ---- setup ----
  k_prep<<<dim3(4), 256, 0, stream>>>(X, Y, x2, kappaf);
  k_computeK<<<dim3(64, 64), dim3(16, 16), 0, stream>>>(X, x2, osp, lsp, Ld);
  run_chol_d(Ld, DinvD, stream);
  k_castL<<<dim3(4096), 256, 0, stream>>>(Ld, Lf);
  k_logdetK<<<dim3(1), 256, 0, stream>>>(Ld, ldetK);
  k_trinv_copy_diag<<<dim3(16), 256, 0, stream>>>(DinvD, Td);
  for (int lev = 1; lev < 16; ++lev)
    k_trinv_off_d<<<dim3(16 - lev), 256, 0, stream>>>(Ld, Td, lev);
  k_syrk_kinv_flip<<<dim3(256), 256, 0, stream>>>(Td, Kinvf);

  // ---- initial Gibbs state ----
  k_gen_eps<<<dim3(80), 256, 0, stream>>>(kiA, kiB, epsb);
  k_init_f2<<<dim3(16, NDRAWS), 256, 0, stream>>>(Lf, epsb, fbuf);
  k_pg<<<dim3(80), 256, 0, stream>>>(koA, koB, fbuf, omega);

  // ---- Gibbs steps ----
  for (int t = 0; t < NSTEPS; ++t){
    k_gen_eps<<<dim3(80), 256, 0, stream>>>(k1A[t], k1B[t], epsb);
    for (int c0 = 0; c0 < NDRAWS; c0 += CH){
      int nb = NDRAWS - c0 < CH ? NDRAWS - c0 : CH;
      k_buildA<<<dim3(1024, nb), 256, 0, stream>>>(Kinvf, omega, bufA, c0, 0);
      run_chol_f(bufA, dinvF, nb, stream);
      k_fwd_solve<<<dim3(nb), 256, 0, stream>>>(bufA, dinvF, kappaf, zbuf);
      k_back_solve_f<<<dim3(nb), 256, 0, stream>>>(bufA, dinvF, zbuf, epsb, fbuf, c0);
    }
    k_pg<<<dim3(80), 256, 0, stream>>>(k2A[t], k2B[t], fbuf, omega);
  }

  // ---- final mll via Woodbury ----
  for (int c0 = 0; c0 < NDRAWS; c0 += CH){
    int nb = NDRAWS - c0 < CH ? NDRAWS - c0 : CH;
    k_buildA<<<dim3(1024, nb), 256, 0, stream>>>(Kinvf, omega, bufA, c0, 1);
    run_chol_f(bufA, dinvF, nb, stream);
    k_final3<<<dim3(nb), 256, 0, stream>>>(bufA, dinvF, kappaf, ldetK, mll, c0);
  }
  k_out<<<dim3(1), 64, 0, stream>>>(mll, out);
}

// Round 6
// 24892.087 us; speedup vs baseline: 3.1789x; 1.3528x over previous
//
#include <hip/hip_runtime.h>
#include <stdint.h>

#define NPTS 1024
#define NDRAWS 20
#define NSTEPS 10
#define NG 100
#define PARTITIONABLE 1

#define TRI(i) (((i) * ((i) + 1)) / 2)
#define NTILE 16
#define NTRI 136                      // 16*17/2
#define AST ((size_t)NTRI * 4096)     // floats per packed lower-tri matrix

typedef unsigned int u32;

// ---------------- threefry2x32 (JAX-compatible, 20 rounds) ----------------
__host__ __device__ static inline void tf2x32(u32 k0, u32 k1, u32 x0, u32 x1, u32* o0, u32* o1){
  u32 ks2 = k0 ^ k1 ^ 0x1BD11BDAu;
  x0 += k0; x1 += k1;
#define TFR(r) { x0 += x1; x1 = (x1 << r) | (x1 >> (32 - r)); x1 ^= x0; }
  TFR(13) TFR(15) TFR(26) TFR(6)
  x0 += k1; x1 += ks2 + 1u;
  TFR(17) TFR(29) TFR(16) TFR(24)
  x0 += ks2; x1 += k0 + 2u;
  TFR(13) TFR(15) TFR(26) TFR(6)
  x0 += k0; x1 += k1 + 3u;
  TFR(17) TFR(29) TFR(16) TFR(24)
  x0 += k1; x1 += ks2 + 4u;
  TFR(13) TFR(15) TFR(26) TFR(6)
  x0 += ks2; x1 += k0 + 5u;
#undef TFR
  *o0 = x0; *o1 = x1;
}

__device__ static inline u32 rand32(u32 ka, u32 kb, u32 i, u32 total){
  u32 a, b;
#if PARTITIONABLE
  (void)total;
  tf2x32(ka, kb, 0u, i, &a, &b);
  return a ^ b;
#else
  u32 h = total >> 1;
  if (i < h){ tf2x32(ka, kb, i, i + h, &a, &b); return a; }
  else      { tf2x32(ka, kb, i - h, i, &a, &b); return b; }
#endif
}

__device__ static inline float u01f(u32 bits){
  return __uint_as_float(0x3F800000u | (bits >> 9)) - 1.0f;
}

// XLA ErfInv32 (Giles) polynomial
__device__ static inline float erfinv32(float x){
  float w = -log1pf(-x * x);
  float p;
  if (w < 5.0f){
    w -= 2.5f;
    p = 2.81022636e-08f;
    p = fmaf(p, w, 3.43273939e-07f);
    p = fmaf(p, w, -3.5233877e-06f);
    p = fmaf(p, w, -4.39150654e-06f);
    p = fmaf(p, w, 0.00021858087f);
    p = fmaf(p, w, -0.00125372503f);
    p = fmaf(p, w, -0.00417768164f);
    p = fmaf(p, w, 0.246640727f);
    p = fmaf(p, w, 1.50140941f);
  } else {
    w = sqrtf(w) - 3.0f;
    p = -0.000200214257f;
    p = fmaf(p, w, 0.000100950558f);
    p = fmaf(p, w, 0.00134934322f);
    p = fmaf(p, w, -0.00367342844f);
    p = fmaf(p, w, 0.00573950773f);
    p = fmaf(p, w, -0.0076224613f);
    p = fmaf(p, w, 0.00943887047f);
    p = fmaf(p, w, 1.00167406f);
    p = fmaf(p, w, 2.83297682f);
  }
  return p * x;
}

__device__ static inline float normal_from_bits(u32 bits){
  const float LO = -0.99999994f;
  float u = u01f(bits);
  float v = u * 2.0f + LO;
  v = fmaxf(LO, v);
  return 1.4142135623730951f * erfinv32(v);
}

__device__ inline float  tsqrt(float x){ return sqrtf(x); }
__device__ inline double tsqrt(double x){ return sqrt(x); }
__device__ inline float  tmax(float a, float b){ return fmaxf(a, b); }
__device__ inline double tmax(double a, double b){ return fmax(a, b); }

__device__ inline void tri_decode(int p, int& ti, int& tj){
  int t = (int)((sqrtf(8.0f * (float)p + 1.0f) - 1.0f) * 0.5f);
  while ((t + 1) * (t + 2) / 2 <= p) ++t;
  while (t * (t + 1) / 2 > p) --t;
  ti = t; tj = p - t * (t + 1) / 2;
}

// interleaved right-looking chol + trinv of a 64x64 tile in LDS (256 threads)
// in:  t = SPD tile.  out: t = L (strict lower + diag restored), Xs = inv(L)
__device__ inline void chol_inv_64(float (*t)[65], float (*Xs)[65], float* diagL, int tid){
  for (int idx = tid; idx < 4096; idx += 256){
    int r = idx >> 6, c = idx & 63;
    Xs[r][c] = (r == c) ? 1.0f : 0.0f;
  }
  __syncthreads();
  for (int j = 0; j < 64; ++j){
    float piv = sqrtf(fmaxf(t[j][j], 1e-30f));
    float inv = 1.0f / piv;
    if (tid < 64){
      int r = j + 1 + tid;
      if (r < 64) t[r][j] *= inv;
      if (tid == 0) diagL[j] = piv;
    } else if (tid < 128){
      Xs[j][tid - 64] *= inv;
    }
    __syncthreads();
    int tg = tid >> 6, tr = tid & 63;
    for (int r2 = j + 1 + tg; r2 < 64; r2 += 4){
      float lj = t[r2][j];
      int c = j + 1 + tr;
      if (c <= r2) t[r2][c] -= lj * t[c][j];
      Xs[r2][tr] = fmaf(-lj, Xs[j][tr], Xs[r2][tr]);
    }
    __syncthreads();
  }
  if (tid < 64) t[tid][tid] = diagL[tid];
  __syncthreads();
}

// ---------------- setup kernels ----------------
__global__ __launch_bounds__(256) void k_prep(const float* X, const int* Y, float* x2, float* kappaf){
  int n = blockIdx.x * 256 + threadIdx.x;
  if (n >= NPTS) return;
  float s = 0.f;
  for (int d = 0; d < 64; ++d){ float v = X[n * 64 + d]; s += v * v; }
  x2[n] = s;
  kappaf[NPTS - 1 - n] = (float)Y[n] - 0.5f;
}

__global__ void k_computeK(const float* X, const float* x2, const float* osp, const float* lsp,
                           double* Ld){
  int j = blockIdx.x * 16 + threadIdx.x;
  int i = blockIdx.y * 16 + threadIdx.y;
  float os = osp[0], ls = lsp[0];
  float dot = 0.f;
  for (int d = 0; d < 64; ++d) dot += X[i * 64 + d] * X[j * 64 + d];
  float d2 = x2[i] + x2[j] - 2.0f * dot;
  d2 = fmaxf(d2, 0.0f);
  float kv = os * expf((-0.5f * d2) / (ls * ls));
  Ld[(size_t)i * NPTS + j] = (double)kv + (i == j ? 1e-6 : 0.0);
}

__global__ __launch_bounds__(256) void k_castL(const double* Ld, float* Lf){
  int idx = blockIdx.x * 256 + threadIdx.x;
  int i = idx >> 10, j = idx & 1023;
  Lf[idx] = (j <= i) ? (float)Ld[idx] : 0.0f;
}

__global__ __launch_bounds__(256) void k_logdetK(const double* Ld, float* ldetK){
  __shared__ double red[4];
  int tid = threadIdx.x;
  double s = 0.0;
  for (int i = tid; i < NPTS; i += 256) s += log(Ld[(size_t)i * NPTS + i]);
  for (int o = 32; o; o >>= 1) s += __shfl_down(s, o);
  if ((tid & 63) == 0) red[tid >> 6] = s;
  __syncthreads();
  if (tid == 0) ldetK[0] = (float)(2.0 * (red[0] + red[1] + red[2] + red[3]));
}

// ---------------- f64 dense blocked Cholesky (setup only) ----------------
__global__ __launch_bounds__(256) void k_chol_diag_inv_d(double* M, double* Dinv, int p){
  double* DI = Dinv + (size_t)p * 4096;
  int k0 = p * 64;
  __shared__ double t[64][65];
  __shared__ double Xs[64][65];
  int tid = threadIdx.x;
  for (int idx = tid; idx < 4096; idx += 256){
    int r = idx >> 6, c = idx & 63;
    t[r][c] = (c <= r) ? M[(size_t)(k0 + r) * NPTS + k0 + c] : 0.0;
    Xs[r][c] = (r == c) ? 1.0 : 0.0;
  }
  __syncthreads();
  for (int j = 0; j < 64; ++j){
    double piv = tsqrt(tmax(t[j][j], 1e-300));
    double inv = 1.0 / piv;
    __syncthreads();
    if (tid == 0) t[j][j] = piv;
    for (int r = j + 1 + tid; r < 64; r += 256) t[r][j] *= inv;
    __syncthreads();
    int tr = tid & 63, tg = tid >> 6;
    for (int r = j + 1 + tg; r < 64; r += 4){
      int c = j + 1 + tr;
      if (c <= r) t[r][c] -= t[r][j] * t[c][j];
    }
    __syncthreads();
  }
  for (int idx = tid; idx < 4096; idx += 256){
    int r = idx >> 6, c = idx & 63;
    M[(size_t)(k0 + r) * NPTS + k0 + c] = (c <= r) ? t[r][c] : 0.0;
  }
  if (tid < 64){
    int c = tid;
    Xs[c][c] = 1.0 / t[c][c];
    for (int r = c + 1; r < 64; ++r){
      double s = 0.0;
      for (int k = c; k < r; ++k) s += t[r][k] * Xs[k][c];
      Xs[r][c] = -s / t[r][r];
    }
    for (int r = 0; r < c; ++r) Xs[r][c] = 0.0;
  }
  __syncthreads();
  for (int idx = tid; idx < 4096; idx += 256){
    int r = idx >> 6, c = idx & 63;
    DI[idx] = Xs[r][c];
  }
}

__global__ __launch_bounds__(256) void k_chol_panel_d(double* M, const double* Dinv, int p){
  const double* DI = Dinv + (size_t)p * 4096;
  int r0 = (p + 1) * 64 + blockIdx.x * 64;
  __shared__ double Rs[64][65];
  __shared__ double Ds[64][65];
  int tid = threadIdx.x;
  for (int idx = tid; idx < 4096; idx += 256){
    int r = idx >> 6, c = idx & 63;
    Rs[r][c] = M[(size_t)(r0 + r) * NPTS + p * 64 + c];
    Ds[r][c] = DI[idx];
  }
  __syncthreads();
  int tx = tid & 15, ty = tid >> 4;
  double acc[4][4];
#pragma unroll
  for (int a = 0; a < 4; ++a)
#pragma unroll
    for (int b = 0; b < 4; ++b) acc[a][b] = 0.0;
  for (int k = 0; k < 64; ++k){
    double av[4], bv[4];
#pragma unroll
    for (int a = 0; a < 4; ++a) av[a] = Rs[ty * 4 + a][k];
#pragma unroll
    for (int b = 0; b < 4; ++b) bv[b] = Ds[tx * 4 + b][k];
#pragma unroll
    for (int a = 0; a < 4; ++a)
#pragma unroll
      for (int b = 0; b < 4; ++b) acc[a][b] += av[a] * bv[b];
  }
#pragma unroll
  for (int a = 0; a < 4; ++a)
#pragma unroll
    for (int b = 0; b < 4; ++b)
      M[(size_t)(r0 + ty * 4 + a) * NPTS + p * 64 + tx * 4 + b] = acc[a][b];
}

__global__ __launch_bounds__(256) void k_chol_update_d(double* M, int k0){
  __shared__ double Pa[64][65];
  __shared__ double Pb[64][65];
  int ti, tj; tri_decode(blockIdx.x, ti, tj);
  int bi = k0 + 64 + ti * 64;
  int bj = k0 + 64 + tj * 64;
  int tid = threadIdx.x;
  for (int idx = tid; idx < 4096; idx += 256){
    int r = idx >> 6, c = idx & 63;
    Pa[r][c] = M[(size_t)(bi + r) * NPTS + k0 + c];
    Pb[r][c] = M[(size_t)(bj + r) * NPTS + k0 + c];
  }
  __syncthreads();
  int tx = tid & 15, ty = tid >> 4;
  double acc[4][4];
#pragma unroll
  for (int a = 0; a < 4; ++a)
#pragma unroll
    for (int b = 0; b < 4; ++b) acc[a][b] = 0.0;
  for (int k = 0; k < 64; ++k){
    double av[4], bv[4];
#pragma unroll
    for (int a = 0; a < 4; ++a) av[a] = Pa[ty * 4 + a][k];
#pragma unroll
    for (int b = 0; b < 4; ++b) bv[b] = Pb[tx * 4 + b][k];
#pragma unroll
    for (int a = 0; a < 4; ++a)
#pragma unroll
      for (int b = 0; b < 4; ++b) acc[a][b] += av[a] * bv[b];
  }
#pragma unroll
  for (int a = 0; a < 4; ++a)
#pragma unroll
    for (int b = 0; b < 4; ++b){
      int gi = bi + ty * 4 + a, gj = bj + tx * 4 + b;
      M[(size_t)gi * NPTS + gj] -= acc[a][b];
    }
}

static void run_chol_d(double* A, double* Dinv, hipStream_t s){
  for (int p = 0; p < 16; ++p){
    k_chol_diag_inv_d<<<dim3(1), 256, 0, s>>>(A, Dinv, p);
    int nrb = 15 - p;
    if (nrb > 0){
      k_chol_panel_d<<<dim3(nrb), 256, 0, s>>>(A, Dinv, p);
      k_chol_update_d<<<dim3(nrb * (nrb + 1) / 2), 256, 0, s>>>(A, p * 64);
    }
  }
}

// ---------------- f64 triangular inverse (one-time, for Kinv) ----------------
__global__ __launch_bounds__(256) void k_trinv_copy_diag(const double* DinvD, double* Td){
  int p = blockIdx.x;
  for (int idx = threadIdx.x; idx < 4096; idx += 256){
    int r = idx >> 6, c = idx & 63;
    Td[(size_t)(p * 64 + r) * NPTS + p * 64 + c] = DinvD[(size_t)p * 4096 + idx];
  }
}

__global__ __launch_bounds__(256) void k_trinv_off_d(const double* Lm, double* Li, int lev){
  const double* M = Lm;
  double* O = Li;
  int J = blockIdx.x, I = J + lev;
  __shared__ double Ta[64][65];
  __shared__ double Tb[64][65];
  int tid = threadIdx.x, tx = tid & 15, ty = tid >> 4;
  double acc[4][4];
#pragma unroll
  for (int a = 0; a < 4; ++a)
#pragma unroll
    for (int b = 0; b < 4; ++b) acc[a][b] = 0.0;
  for (int K = J; K < I; ++K){
    __syncthreads();
    for (int idx = tid; idx < 4096; idx += 256){
      int r = idx >> 6, c = idx & 63;
      Ta[r][c] = M[(size_t)(I * 64 + r) * NPTS + K * 64 + c];
      Tb[r][c] = O[(size_t)(K * 64 + r) * NPTS + J * 64 + c];
    }
    __syncthreads();
    for (int k = 0; k < 64; ++k){
      double av[4], bv[4];
#pragma unroll
      for (int a = 0; a < 4; ++a) av[a] = Ta[ty * 4 + a][k];
#pragma unroll
      for (int b = 0; b < 4; ++b) bv[b] = Tb[k][tx * 4 + b];
#pragma unroll
      for (int a = 0; a < 4; ++a)
#pragma unroll
        for (int b = 0; b < 4; ++b) acc[a][b] += av[a] * bv[b];
    }
  }
  __syncthreads();
#pragma unroll
  for (int a = 0; a < 4; ++a)
#pragma unroll
    for (int b = 0; b < 4; ++b) Tb[ty * 4 + a][tx * 4 + b] = acc[a][b];
  for (int idx = tid; idx < 4096; idx += 256){
    int r = idx >> 6, c = idx & 63;
    Ta[r][c] = O[(size_t)(I * 64 + r) * NPTS + I * 64 + c];
  }
  __syncthreads();
  double ac2[4][4];
#pragma unroll
  for (int a = 0; a < 4; ++a)
#pragma unroll
    for (int b = 0; b < 4; ++b) ac2[a][b] = 0.0;
  for (int k = 0; k < 64; ++k){
    double av[4], bv[4];
#pragma unroll
    for (int a = 0; a < 4; ++a) av[a] = Ta[ty * 4 + a][k];
#pragma unroll
    for (int b = 0; b < 4; ++b) bv[b] = Tb[k][tx * 4 + b];
#pragma unroll
    for (int a = 0; a < 4; ++a)
#pragma unroll
      for (int b = 0; b < 4; ++b) ac2[a][b] += av[a] * bv[b];
  }
#pragma unroll
  for (int a = 0; a < 4; ++a)
#pragma unroll
    for (int b = 0; b < 4; ++b)
      O[(size_t)(I * 64 + ty * 4 + a) * NPTS + J * 64 + tx * 4 + b] = -ac2[a][b];
}

// packed flipped Kinv: for block pair (ti<=tj), write tile (15-ti, 15-tj) of P*Kinv*P
__global__ __launch_bounds__(256) void k_syrk_kinv_flip(const double* Td, float* Kinvp){
  int a0, b0; tri_decode(blockIdx.x, a0, b0);   // a0 >= b0
  int ti = b0, tj = a0;                          // ti <= tj
  int kmin = tj;
  __shared__ double Ta[64][65];
  __shared__ double Tb[64][65];
  int tid = threadIdx.x, tx = tid & 15, ty = tid >> 4;
  double acc[4][4];
#pragma unroll
  for (int a = 0; a < 4; ++a)
#pragma unroll
    for (int b = 0; b < 4; ++b) acc[a][b] = 0.0;
  for (int K = kmin; K < 16; ++K){
    __syncthreads();
    for (int idx = tid; idx < 4096; idx += 256){
      int r = idx >> 6, c = idx & 63;
      Ta[r][c] = Td[(size_t)(K * 64 + r) * NPTS + ti * 64 + c];
      Tb[r][c] = Td[(size_t)(K * 64 + r) * NPTS + tj * 64 + c];
    }
    __syncthreads();
    for (int k = 0; k < 64; ++k){
      double av[4], bv[4];
#pragma unroll
      for (int a = 0; a < 4; ++a) av[a] = Ta[k][ty * 4 + a];
#pragma unroll
      for (int b = 0; b < 4; ++b) bv[b] = Tb[k][tx * 4 + b];
#pragma unroll
      for (int a = 0; a < 4; ++a)
#pragma unroll
        for (int b = 0; b < 4; ++b) acc[a][b] += av[a] * bv[b];
    }
  }
  int tileR = 15 - ti, tileC = 15 - tj;          // tileR >= tileC
  float* out = Kinvp + (size_t)(TRI(tileR) + tileC) * 4096;
#pragma unroll
  for (int a = 0; a < 4; ++a)
#pragma unroll
    for (int b = 0; b < 4; ++b){
      int rin = 63 - (ty * 4 + a), cin = 63 - (tx * 4 + b);
      out[rin * 64 + cin] = (float)acc[a][b];
    }
}

// ---------------- per-step kernels (packed f32) ----------------
__global__ __launch_bounds__(256) void k_buildA(const float* Kinvp, const float* omega, float* Ab,
                                                int c0, int clip){
  int d = c0 + blockIdx.y;
  float* A = Ab + (size_t)blockIdx.y * AST;
  int idx4 = blockIdx.x * 256 + threadIdx.x;     // 0..139263
  float4 v = ((const float4*)Kinvp)[idx4];
  int tile = idx4 >> 10;
  int ti, tj; tri_decode(tile, ti, tj);
  if (ti == tj){
    int e = (idx4 & 1023) * 4;
    int r = e >> 6, c = e & 63;
    if (c <= r && r < c + 4){
      float om = omega[(size_t)d * NPTS + (NPTS - 1 - (ti * 64 + r))];
      if (clip) om = fmaxf(om, 1e-16f);
      ((float*)&v)[r - c] += om;
    }
  }
  ((float4*)A)[idx4] = v;
}

// first diag tile chol+inv
__global__ __launch_bounds__(256) void k_diag0(float* Ab, float* Dinv){
  float* M = Ab + (size_t)blockIdx.x * AST;
  float* DI = Dinv + (size_t)blockIdx.x * 16 * 4096;
  __shared__ float t[64][65];
  __shared__ float Xs[64][65];
  __shared__ float diagL[64];
  int tid = threadIdx.x;
  for (int idx = tid; idx < 1024; idx += 256){
    float4 v = ((const float4*)M)[idx];
    int e = idx * 4, r = e >> 6, c = e & 63;
    t[r][c] = v.x; t[r][c + 1] = v.y; t[r][c + 2] = v.z; t[r][c + 3] = v.w;
  }
  __syncthreads();
  chol_inv_64(t, Xs, diagL, tid);
  for (int idx = tid; idx < 1024; idx += 256){
    int e = idx * 4, r = e >> 6, c = e & 63;
    float4 v, w;
    v.x = (c     <= r) ? t[r][c]     : 0.f;
    v.y = (c + 1 <= r) ? t[r][c + 1] : 0.f;
    v.z = (c + 2 <= r) ? t[r][c + 2] : 0.f;
    v.w = (c + 3 <= r) ? t[r][c + 3] : 0.f;
    w.x = Xs[r][c]; w.y = Xs[r][c + 1]; w.z = Xs[r][c + 2]; w.w = Xs[r][c + 3];
    ((float4*)M)[idx] = v;
    ((float4*)DI)[idx] = w;
  }
}

// panel: L(rt,p) = A(rt,p) * DI(p)^T
__global__ __launch_bounds__(256) void k_panel(float* Ab, const float* Dinv, int p){
  float* M = Ab + (size_t)blockIdx.y * AST;
  const float* DI = Dinv + ((size_t)blockIdx.y * 16 + p) * 4096;
  int rt = p + 1 + blockIdx.x;
  float* R = M + (size_t)(TRI(rt) + p) * 4096;
  __shared__ float Rs[64][65];
  __shared__ float Ds[64][65];
  int tid = threadIdx.x;
  for (int idx = tid; idx < 1024; idx += 256){
    float4 v = ((const float4*)R)[idx];
    float4 w = ((const float4*)DI)[idx];
    int e = idx * 4, r = e >> 6, c = e & 63;
    Rs[r][c] = v.x; Rs[r][c + 1] = v.y; Rs[r][c + 2] = v.z; Rs[r][c + 3] = v.w;
    Ds[r][c] = w.x; Ds[r][c + 1] = w.y; Ds[r][c + 2] = w.z; Ds[r][c + 3] = w.w;
  }
  __syncthreads();
  int tx = tid & 15, ty = tid >> 4;
  float acc[4][4];
#pragma unroll
  for (int a = 0; a < 4; ++a)
#pragma unroll
    for (int b = 0; b < 4; ++b) acc[a][b] = 0.f;
  for (int k = 0; k < 64; ++k){
    float av[4], bv[4];
#pragma unroll
    for (int a = 0; a < 4; ++a) av[a] = Rs[ty * 4 + a][k];
#pragma unroll
    for (int b = 0; b < 4; ++b) bv[b] = Ds[tx * 4 + b][k];
#pragma unroll
    for (int a = 0; a < 4; ++a)
#pragma unroll
      for (int b = 0; b < 4; ++b) acc[a][b] += av[a] * bv[b];
  }
  __syncthreads();
#pragma unroll
  for (int a = 0; a < 4; ++a)
#pragma unroll
    for (int b = 0; b < 4; ++b) Rs[ty * 4 + a][tx * 4 + b] = acc[a][b];
  __syncthreads();
  for (int idx = tid; idx < 1024; idx += 256){
    int e = idx * 4, r = e >> 6, c = e & 63;
    float4 v;
    v.x = Rs[r][c]; v.y = Rs[r][c + 1]; v.z = Rs[r][c + 2]; v.w = Rs[r][c + 3];
    ((float4*)R)[idx] = v;
  }
}

// trailing update; block 0 (tile (p+1,p+1)) additionally runs chol+inv of its tile
__global__ __launch_bounds__(256) void k_update_diag(float* Ab, float* Dinv, int p){
  float* M = Ab + (size_t)blockIdx.y * AST;
  __shared__ float Pa[64][65];
  __shared__ float Pb[64][65];
  __shared__ float diagL[64];
  int t0, t1; tri_decode(blockIdx.x, t0, t1);    // t0 >= t1
  int bi = p + 1 + t0, bj = p + 1 + t1;
  const float* La = M + (size_t)(TRI(bi) + p) * 4096;
  const float* Lb = M + (size_t)(TRI(bj) + p) * 4096;
  float* Atile = M + (size_t)(TRI(bi) + bj) * 4096;
  int tid = threadIdx.x;
  for (int idx = tid; idx < 1024; idx += 256){
    float4 v = ((const float4*)La)[idx];
    float4 w = ((const float4*)Lb)[idx];
    int e = idx * 4, r = e >> 6, c = e & 63;
    Pa[r][c] = v.x; Pa[r][c + 1] = v.y; Pa[r][c + 2] = v.z; Pa[r][c + 3] = v.w;
    Pb[r][c] = w.x; Pb[r][c + 1] = w.y; Pb[r][c + 2] = w.z; Pb[r][c + 3] = w.w;
  }
  __syncthreads();
  int tx = tid & 15, ty = tid >> 4;
  float acc[4][4];
#pragma unroll
  for (int a = 0; a < 4; ++a)
#pragma unroll
    for (int b = 0; b < 4; ++b) acc[a][b] = 0.f;
  for (int k = 0; k < 64; ++k){
    float av[4], bv[4];
#pragma unroll
    for (int a = 0; a < 4; ++a) av[a] = Pa[ty * 4 + a][k];
#pragma unroll
    for (int b = 0; b < 4; ++b) bv[b] = Pb[tx * 4 + b][k];
#pragma unroll
    for (int a = 0; a < 4; ++a)
#pragma unroll
      for (int b = 0; b < 4; ++b) acc[a][b] += av[a] * bv[b];
  }
  __syncthreads();
  // load A tile into Pa, subtract product
  for (int idx = tid; idx < 1024; idx += 256){
    float4 v = ((const float4*)Atile)[idx];
    int e = idx * 4, r = e >> 6, c = e & 63;
    Pa[r][c] = v.x; Pa[r][c + 1] = v.y; Pa[r][c + 2] = v.z; Pa[r][c + 3] = v.w;
  }
  __syncthreads();
#pragma unroll
  for (int a = 0; a < 4; ++a)
#pragma unroll
    for (int b = 0; b < 4; ++b)
      Pa[ty * 4 + a][tx * 4 + b] -= acc[a][b];
  __syncthreads();
  if (blockIdx.x == 0){
    // this is tile (p+1, p+1): chol + inverse in place
    float* DI = Dinv + ((size_t)blockIdx.y * 16 + (p + 1)) * 4096;
    chol_inv_64(Pa, Pb, diagL, tid);
    for (int idx = tid; idx < 1024; idx += 256){
      int e = idx * 4, r = e >> 6, c = e & 63;
      float4 v, w;
      v.x = (c     <= r) ? Pa[r][c]     : 0.f;
      v.y = (c + 1 <= r) ? Pa[r][c + 1] : 0.f;
      v.z = (c + 2 <= r) ? Pa[r][c + 2] : 0.f;
      v.w = (c + 3 <= r) ? Pa[r][c + 3] : 0.f;
      w.x = Pb[r][c]; w.y = Pb[r][c + 1]; w.z = Pb[r][c + 2]; w.w = Pb[r][c + 3];
      ((float4*)Atile)[idx] = v;
      ((float4*)DI)[idx] = w;
    }
  } else {
    for (int idx = tid; idx < 1024; idx += 256){
      int e = idx * 4, r = e >> 6, c = e & 63;
      float4 v;
      v.x = Pa[r][c]; v.y = Pa[r][c + 1]; v.z = Pa[r][c + 2]; v.w = Pa[r][c + 3];
      ((float4*)Atile)[idx] = v;
    }
  }
}

static void run_chol_f(float* A, float* Dinv, int batch, hipStream_t s){
  k_diag0<<<dim3(batch), 256, 0, s>>>(A, Dinv);
  for (int p = 0; p < 15; ++p){
    int nrb = 15 - p;
    k_panel<<<dim3(nrb, batch), 256, 0, s>>>(A, Dinv, p);
    k_update_diag<<<dim3(nrb * (nrb + 1) / 2, batch), 256, 0, s>>>(A, Dinv, p);
  }
}

// ---------------- triangular solves (packed, double-buffered) ----------------
__global__ __launch_bounds__(256) void k_fwd_solve(const float* Ab, const float* DinvF,
                                                   const float* kappaf, float* zbuf){
  int d0 = blockIdx.x;
  const float* L = Ab + (size_t)d0 * AST;
  const float* DI = DinvF + (size_t)d0 * 16 * 4096;
  __shared__ float z[NPTS];
  __shared__ float buf[2][64 * 65];
  __shared__ float part[4][64];
  int tid = threadIdx.x;
  float4 rg[4];
  auto loadDI = [&](int p){
#pragma unroll
    for (int j = 0; j < 4; ++j)
      rg[j] = *(const float4*)&DI[p * 4096 + j * 1024 + tid * 4];
  };
  auto loadL = [&](int rbrow, int pcol){
    const float* T = L + (size_t)(TRI(rbrow) + pcol) * 4096;
#pragma unroll
    for (int j = 0; j < 4; ++j)
      rg[j] = *(const float4*)&T[j * 1024 + tid * 4];
  };
  auto store = [&](int cur){
#pragma unroll
    for (int j = 0; j < 4; ++j){
      int e = j * 1024 + tid * 4; int r = e >> 6, c = e & 63;
      float* b = &buf[cur][r * 65 + c];
      b[0] = rg[j].x; b[1] = rg[j].y; b[2] = rg[j].z; b[3] = rg[j].w;
    }
  };
  for (int i = tid; i < NPTS; i += 256) z[i] = kappaf[i];
  loadDI(0);
  int cur = 0;
  for (int p = 0; p < 16; ++p){
    for (int rb = p; rb < 16; ++rb){
      store(cur);
      int np = p, nrb = rb + 1;
      if (nrb >= 16){ np = p + 1; nrb = np; }
      if (np < 16){ if (nrb == np) loadDI(np); else loadL(nrb, np); }
      __syncthreads();
      int rr = tid & 63, q = tid >> 6;
      float s = 0.f;
#pragma unroll
      for (int cc = 0; cc < 16; ++cc)
        s += buf[cur][rr * 65 + q * 16 + cc] * z[p * 64 + q * 16 + cc];
      part[q][rr] = s;
      __syncthreads();
      if (tid < 64){
        float v = part[0][tid] + part[1][tid] + part[2][tid] + part[3][tid];
        if (rb == p) z[p * 64 + tid] = v;
        else z[rb * 64 + tid] -= v;
      }
      __syncthreads();
      cur ^= 1;
    }
  }
  for (int i = tid; i < NPTS; i += 256) zbuf[(size_t)d0 * NPTS + i] = z[i];
}

__global__ __launch_bounds__(256) void k_back_solve_f(const float* Ab, const float* DinvF,
                                                      const float* zbuf, const float* eps,
                                                      float* fbuf, int c0){
  int d0 = blockIdx.x, d = c0 + d0;
  const float* L = Ab + (size_t)d0 * AST;
  const float* DI = DinvF + (size_t)d0 * 16 * 4096;
  __shared__ float z1[NPTS], z2[NPTS];
  __shared__ float buf[2][64 * 65];
  __shared__ float p1[4][64], p2[4][64];
  int tid = threadIdx.x;
  float4 rg[4];
  auto loadDI = [&](int p){
#pragma unroll
    for (int j = 0; j < 4; ++j)
      rg[j] = *(const float4*)&DI[p * 4096 + j * 1024 + tid * 4];
  };
  auto loadL = [&](int prow, int cbcol){
    const float* T = L + (size_t)(TRI(prow) + cbcol) * 4096;
#pragma unroll
    for (int j = 0; j < 4; ++j)
      rg[j] = *(const float4*)&T[j * 1024 + tid * 4];
  };
  auto store = [&](int cur){
#pragma unroll
    for (int j = 0; j < 4; ++j){
      int e = j * 1024 + tid * 4; int r = e >> 6, c = e & 63;
      float* b = &buf[cur][r * 65 + c];
      b[0] = rg[j].x; b[1] = rg[j].y; b[2] = rg[j].z; b[3] = rg[j].w;
    }
  };
  for (int i = tid; i < NPTS; i += 256){
    z1[i] = zbuf[(size_t)d0 * NPTS + i];
    z2[NPTS - 1 - i] = eps[(size_t)d * NPTS + i];
  }
  loadDI(15);
  int cur = 0;
  for (int p = 15; p >= 0; --p){
    for (int cb = p; cb >= 0; --cb){
      store(cur);
      int np = p, ncb = cb - 1;
      if (ncb < 0){ np = p - 1; ncb = np; }
      if (np >= 0){ if (ncb == np) loadDI(np); else loadL(np, ncb); }
      __syncthreads();
      int cc = tid & 63, q = tid >> 6;
      float s1 = 0.f, s2 = 0.f;
#pragma unroll
      for (int rr = 0; rr < 16; ++rr){
        float t = buf[cur][(q * 16 + rr) * 65 + cc];
        s1 += t * z1[p * 64 + q * 16 + rr];
        s2 += t * z2[p * 64 + q * 16 + rr];
      }
      p1[q][cc] = s1; p2[q][cc] = s2;
      __syncthreads();
      if (tid < 64){
        float v1 = p1[0][tid] + p1[1][tid] + p1[2][tid] + p1[3][tid];
        float v2 = p2[0][tid] + p2[1][tid] + p2[2][tid] + p2[3][tid];
        if (cb == p){ z1[p * 64 + tid] = v1; z2[p * 64 + tid] = v2; }
        else { z1[cb * 64 + tid] -= v1; z2[cb * 64 + tid] -= v2; }
      }
      __syncthreads();
      cur ^= 1;
    }
  }
  for (int i = tid; i < NPTS; i += 256)
    fbuf[(size_t)d * NPTS + i] = z1[NPTS - 1 - i] + z2[NPTS - 1 - i];
}

// fused final (Woodbury): mll = 0.5*||Lb^-1 kappaf||^2 + sum log diag(DI) - 0.5*ldetK - N log2
__global__ __launch_bounds__(256) void k_final3(const float* Ab, const float* DinvF,
                                                const float* kappaf, const float* ldetK,
                                                float* mll, int c0){
  int d0 = blockIdx.x, d = c0 + d0;
  const float* L = Ab + (size_t)d0 * AST;
  const float* DI = DinvF + (size_t)d0 * 16 * 4096;
  __shared__ float z[NPTS];
  __shared__ float buf[2][64 * 65];
  __shared__ float part[4][64];
  __shared__ float redq[4];
  int tid = threadIdx.x;
  float4 rg[4];
  auto loadDI = [&](int p){
#pragma unroll
    for (int j = 0; j < 4; ++j)
      rg[j] = *(const float4*)&DI[p * 4096 + j * 1024 + tid * 4];
  };
  auto loadL = [&](int rbrow, int pcol){
    const float* T = L + (size_t)(TRI(rbrow) + pcol) * 4096;
#pragma unroll
    for (int j = 0; j < 4; ++j)
      rg[j] = *(const float4*)&T[j * 1024 + tid * 4];
  };
  auto store = [&](int cur){
#pragma unroll
    for (int j = 0; j < 4; ++j){
      int e = j * 1024 + tid * 4; int r = e >> 6, c = e & 63;
      float* b = &buf[cur][r * 65 + c];
      b[0] = rg[j].x; b[1] = rg[j].y; b[2] = rg[j].z; b[3] = rg[j].w;
    }
  };
  for (int i = tid; i < NPTS; i += 256) z[i] = kappaf[i];
  loadDI(0);
  int cur = 0;
  float ldacc = 0.f;
  for (int p = 0; p < 16; ++p){
    for (int rb = p; rb < 16; ++rb){
      store(cur);
      int np = p, nrb = rb + 1;
      if (nrb >= 16){ np = p + 1; nrb = np; }
      if (np < 16){ if (nrb == np) loadDI(np); else loadL(nrb, np); }
      __syncthreads();
      if (rb == p && tid < 64) ldacc += logf(buf[cur][tid * 65 + tid]);
      int rr = tid & 63, q = tid >> 6;
      float s = 0.f;
#pragma unroll
      for (int cc = 0; cc < 16; ++cc)
        s += buf[cur][rr * 65 + q * 16 + cc] * z[p * 64 + q * 16 + cc];
      part[q][rr] = s;
      __syncthreads();
      if (tid < 64){
        float v = part[0][tid] + part[1][tid] + part[2][tid] + part[3][tid];
        if (rb == p) z[p * 64 + tid] = v;
        else z[rb * 64 + tid] -= v;
      }
      __syncthreads();
      cur ^= 1;
    }
  }
  float q2 = 0.f;
  for (int i = tid; i < NPTS; i += 256) q2 += z[i] * z[i];
  int wid = tid >> 6, lane = tid & 63;
  for (int o = 32; o; o >>= 1) q2 += __shfl_down(q2, o);
  if (lane == 0) redq[wid] = q2;
  __syncthreads();
  if (tid < 64){
    float ldv = ldacc;
    for (int o = 32; o; o >>= 1) ldv += __shfl_down(ldv, o);
    if (tid == 0){
      float q2t = redq[0] + redq[1] + redq[2] + redq[3];
      mll[d] = 0.5f * q2t + ldv - 0.5f * ldetK[0] - 709.7827128933839f;
    }
  }
}

// ---------------- RNG kernels ----------------
__global__ __launch_bounds__(256) void k_gen_eps(u32 ka, u32 kb, float* eps){
  int i = blockIdx.x * 256 + threadIdx.x;
  if (i >= NDRAWS * NPTS) return;
  u32 bits = rand32(ka, kb, (u32)i, (u32)(NDRAWS * NPTS));
  eps[i] = normal_from_bits(bits);
}

__global__ __launch_bounds__(256) void k_init_f2(const float* Lf, const float* eps, float* f){
  int d = blockIdx.y, rb = blockIdx.x;
  __shared__ float tile[64][65];
  __shared__ float ev[64];
  __shared__ float part[4][64];
  int tid = threadIdx.x;
  int r = tid & 63, q = tid >> 6;
  float acc = 0.f;
  for (int kt = 0; kt <= rb; ++kt){
    __syncthreads();
#pragma unroll
    for (int j = 0; j < 4; ++j){
      int e = j * 1024 + tid * 4; int rr = e >> 6, cc = e & 63;
      float4 v = *(const float4*)&Lf[(size_t)(rb * 64 + rr) * NPTS + kt * 64 + cc];
      tile[rr][cc] = v.x; tile[rr][cc + 1] = v.y; tile[rr][cc + 2] = v.z; tile[rr][cc + 3] = v.w;
    }
    if (tid < 64) ev[tid] = eps[(size_t)d * NPTS + kt * 64 + tid];
    __syncthreads();
    int cmax = (kt == rb) ? (r + 1) : 64;
    for (int cc = q * 16; cc < q * 16 + 16; ++cc){
      if (cc < cmax) acc += tile[r][cc] * ev[cc];
    }
  }
  part[q][r] = acc;
  __syncthreads();
  if (tid < 64){
    float s = part[0][tid] + part[1][tid] + part[2][tid] + part[3][tid];
    f[(size_t)d * NPTS + rb * 64 + tid] = s;
  }
}

__global__ __launch_bounds__(256) void k_pg(u32 ka, u32 kb, const float* f, float* omega){
  int idx = blockIdx.x * 256 + threadIdx.x;
  if (idx >= NDRAWS * NPTS) return;
  float c = f[idx];
  float c2w = (c * c) / 39.47841760435743f;
  float sum = 0.f;
  u32 base = (u32)idx * NG;
  for (int g = 0; g < NG; ++g){
    u32 bits = rand32(ka, kb, base + (u32)g, (u32)(NDRAWS * NPTS * NG));
    float u = u01f(bits);
    float e = -log1pf(-u);
    float kk = (float)g + 0.5f;
    sum += e / (kk * kk + c2w);
  }
  omega[idx] = sum / 19.739208802178716f;
}

__global__ void k_out(const float* mll, float* out){
  if (threadIdx.x == 0){
    float s = 0.f;
    for (int dd = 0; dd < NDRAWS; ++dd) s += mll[dd];
    float m = s / (float)NDRAWS;
    out[0] = (-m) / (float)NPTS;
  }
}

// ---------------- host-side key derivation ----------------
static void host_split(u32 ka, u32 kb, int num, u32* outA, u32* outB){
#if PARTITIONABLE
  for (int j = 0; j < num; ++j) tf2x32(ka, kb, 0u, (u32)j, &outA[j], &outB[j]);
#else
  u32 flat[40];
  for (int k = 0; k < num; ++k){
    u32 a, b; tf2x32(ka, kb, (u32)k, (u32)(num + k), &a, &b);
    flat[k] = a; flat[num + k] = b;
  }
  for (int j = 0; j < num; ++j){ outA[j] = flat[2 * j]; outB[j] = flat[2 * j + 1]; }
#endif
}

extern "C" void kernel_launch(void* const* d_in, const int* in_sizes, int n_in,
                              void* d_out, int out_size, void* d_ws, size_t ws_size,
                              hipStream_t stream){
  const float* X  = (const float*)d_in[0];
  const int*   Y  = (const int*)d_in[1];
  const float* osp = (const float*)d_in[2];
  const float* lsp = (const float*)d_in[3];
  float* out = (float*)d_out;

  const size_t NN = (size_t)NPTS * NPTS;
  char* p = (char*)d_ws;
  // ---- persistent region (~2.5 MB) ----
  float* Kinvp  = (float*)p;  p += AST * 4;
  float* omega  = (float*)p;  p += (size_t)NDRAWS * NPTS * 4;
  float* fbuf   = (float*)p;  p += (size_t)NDRAWS * NPTS * 4;
  float* epsb   = (float*)p;  p += (size_t)NDRAWS * NPTS * 4;
  float* kappaf = (float*)p;  p += NPTS * 4;
  float* x2     = (float*)p;  p += NPTS * 4;
  float* mll    = (float*)p;  p += 128;
  float* ldetK  = (float*)p;  p += 128;
  uintptr_t ip = (uintptr_t)p; ip = (ip + 255) & ~(uintptr_t)255;
  char* cb = (char*)ip;

  // ---- setup-only aliases (used strictly before the Gibbs loop) ----
  double* Ld    = (double*)cb;                       // 8 MB
  double* Td    = (double*)(cb + NN * 8);            // 8 MB
  double* DinvD = (double*)(cb + NN * 16);           // 512 KB
  float*  Lf    = (float*)(cb + NN * 16 + (size_t)16 * 4096 * 8);  // 4 MB

  // ---- chunk buffers (overlay same region) ----
  size_t rem = ws_size - (size_t)(cb - (char*)d_ws);
  const size_t PER_DRAW = AST * 4 + (size_t)16 * 4096 * 4 + NPTS * 4;
  int CH = (int)(rem / PER_DRAW);
  if (CH > NDRAWS) CH = NDRAWS;
  if (CH < 1) CH = 1;
  float* bufA  = (float*)cb;
  float* dinvF = (float*)(cb + (size_t)CH * AST * 4);
  float* zbuf  = (float*)(cb + (size_t)CH * (AST * 4 + (size_t)16 * 4096 * 4));

  // ---- keys ----
  u32 r3A[3], r3B[3];
  host_split(0u, 42u, 3, r3A, r3B);
  u32 kiA = r3A[0], kiB = r3B[0];
  u32 koA = r3A[1], koB = r3B[1];
  u32 klA = r3A[2], klB = r3B[2];
  u32 kkA[NSTEPS], kkB[NSTEPS];
  host_split(klA, klB, NSTEPS, kkA, kkB);
  u32 k1A[NSTEPS], k1B[NSTEPS], k2A[NSTEPS], k2B[NSTEPS];
  for (int t = 0; t < NSTEPS; ++t){
    u32 sA[2], sB[2];
    host_split(kkA[t], kkB[t], 2, sA, sB);
    k1A[t] = sA[0]; k1B[t] = sB[0];
    k2A[t] = sA[1]; k2B[t] = sB[1];
  }

  // ---- setup: K (f64), chol, Lf, logdet, trinv, packed flipped Kinv ----
  k_prep<<<dim3(4), 256, 0, stream>>>(X, Y, x2, kappaf);
  k_computeK<<<dim3(64, 64), dim3(16, 16), 0, stream>>>(X, x2, osp, lsp, Ld);
  run_chol_d(Ld, DinvD, stream);
  k_castL<<<dim3(4096), 256, 0, stream>>>(Ld, Lf);
  k_logdetK<<<dim3(1), 256, 0, stream>>>(Ld, ldetK);
  k_trinv_copy_diag<<<dim3(16), 256, 0, stream>>>(DinvD, Td);
  for (int lev = 1; lev < 16; ++lev)
    k_trinv_off_d<<<dim3(16 - lev), 256, 0, stream>>>(Ld, Td, lev);
  k_syrk_kinv_flip<<<dim3(NTRI), 256, 0, stream>>>(Td, Kinvp);

  // ---- initial Gibbs state ----
  k_gen_eps<<<dim3(80), 256, 0, stream>>>(kiA, kiB, epsb);
  k_init_f2<<<dim3(16, NDRAWS), 256, 0, stream>>>(Lf, epsb, fbuf);
  k_pg<<<dim3(80), 256, 0, stream>>>(koA, koB, fbuf, omega);

  // ---- Gibbs steps ----
  for (int t = 0; t < NSTEPS; ++t){
    k_gen_eps<<<dim3(80), 256, 0, stream>>>(k1A[t], k1B[t], epsb);
    for (int c0 = 0; c0 < NDRAWS; c0 += CH){
      int nb = NDRAWS - c0 < CH ? NDRAWS - c0 : CH;
      k_buildA<<<dim3(544, nb), 256, 0, stream>>>(Kinvp, omega, bufA, c0, 0);
      run_chol_f(bufA, dinvF, nb, stream);
      k_fwd_solve<<<dim3(nb), 256, 0, stream>>>(bufA, dinvF, kappaf, zbuf);
      k_back_solve_f<<<dim3(nb), 256, 0, stream>>>(bufA, dinvF, zbuf, epsb, fbuf, c0);
    }
    k_pg<<<dim3(80), 256, 0, stream>>>(k2A[t], k2B[t], fbuf, omega);
  }

  // ---- final mll (Woodbury) ----
  for (int c0 = 0; c0 < NDRAWS; c0 += CH){
    int nb = NDRAWS - c0 < CH ? NDRAWS - c0 : CH;
    k_buildA<<<dim3(544, nb), 256, 0, stream>>>(Kinvp, omega, bufA, c0, 1);
    run_chol_f(bufA, dinvF, nb, stream);
    k_final3<<<dim3(nb), 256, 0, stream>>>(bufA, dinvF, kappaf, ldetK, mll, c0);
  }
  k_out<<<dim3(1), 64, 0, stream>>>(mll, out);
}

// Round 7
// 23155.440 us; speedup vs baseline: 3.4173x; 1.0750x over previous
//
#include <hip/hip_runtime.h>
#include <stdint.h>

#define NPTS 1024
#define NDRAWS 20
#define NSTEPS 10
#define NG 100
#define PARTITIONABLE 1

#define TRI(i) (((i) * ((i) + 1)) / 2)
#define NTRI 136                      // 16*17/2
#define AST ((size_t)NTRI * 4096)     // floats per packed lower-tri matrix

typedef unsigned int u32;

// ---------------- threefry2x32 (JAX-compatible, 20 rounds) ----------------
__host__ __device__ static inline void tf2x32(u32 k0, u32 k1, u32 x0, u32 x1, u32* o0, u32* o1){
  u32 ks2 = k0 ^ k1 ^ 0x1BD11BDAu;
  x0 += k0; x1 += k1;
#define TFR(r) { x0 += x1; x1 = (x1 << r) | (x1 >> (32 - r)); x1 ^= x0; }
  TFR(13) TFR(15) TFR(26) TFR(6)
  x0 += k1; x1 += ks2 + 1u;
  TFR(17) TFR(29) TFR(16) TFR(24)
  x0 += ks2; x1 += k0 + 2u;
  TFR(13) TFR(15) TFR(26) TFR(6)
  x0 += k0; x1 += k1 + 3u;
  TFR(17) TFR(29) TFR(16) TFR(24)
  x0 += k1; x1 += ks2 + 4u;
  TFR(13) TFR(15) TFR(26) TFR(6)
  x0 += ks2; x1 += k0 + 5u;
#undef TFR
  *o0 = x0; *o1 = x1;
}

__device__ static inline u32 rand32(u32 ka, u32 kb, u32 i, u32 total){
  u32 a, b;
#if PARTITIONABLE
  (void)total;
  tf2x32(ka, kb, 0u, i, &a, &b);
  return a ^ b;
#else
  u32 h = total >> 1;
  if (i < h){ tf2x32(ka, kb, i, i + h, &a, &b); return a; }
  else      { tf2x32(ka, kb, i - h, i, &a, &b); return b; }
#endif
}

__device__ static inline float u01f(u32 bits){
  return __uint_as_float(0x3F800000u | (bits >> 9)) - 1.0f;
}

// XLA ErfInv32 (Giles) polynomial
__device__ static inline float erfinv32(float x){
  float w = -log1pf(-x * x);
  float p;
  if (w < 5.0f){
    w -= 2.5f;
    p = 2.81022636e-08f;
    p = fmaf(p, w, 3.43273939e-07f);
    p = fmaf(p, w, -3.5233877e-06f);
    p = fmaf(p, w, -4.39150654e-06f);
    p = fmaf(p, w, 0.00021858087f);
    p = fmaf(p, w, -0.00125372503f);
    p = fmaf(p, w, -0.00417768164f);
    p = fmaf(p, w, 0.246640727f);
    p = fmaf(p, w, 1.50140941f);
  } else {
    w = sqrtf(w) - 3.0f;
    p = -0.000200214257f;
    p = fmaf(p, w, 0.000100950558f);
    p = fmaf(p, w, 0.00134934322f);
    p = fmaf(p, w, -0.00367342844f);
    p = fmaf(p, w, 0.00573950773f);
    p = fmaf(p, w, -0.0076224613f);
    p = fmaf(p, w, 0.00943887047f);
    p = fmaf(p, w, 1.00167406f);
    p = fmaf(p, w, 2.83297682f);
  }
  return p * x;
}

__device__ static inline float normal_from_bits(u32 bits){
  const float LO = -0.99999994f;
  float u = u01f(bits);
  float v = u * 2.0f + LO;
  v = fmaxf(LO, v);
  return 1.4142135623730951f * erfinv32(v);
}

__device__ inline float  tsqrt(float x){ return sqrtf(x); }
__device__ inline double tsqrt(double x){ return sqrt(x); }
__device__ inline float  tmax(float a, float b){ return fmaxf(a, b); }
__device__ inline double tmax(double a, double b){ return fmax(a, b); }

__device__ inline void tri_decode(int p, int& ti, int& tj){
  int t = (int)((sqrtf(8.0f * (float)p + 1.0f) - 1.0f) * 0.5f);
  while ((t + 1) * (t + 2) / 2 <= p) ++t;
  while (t * (t + 1) / 2 > p) --t;
  ti = t; tj = p - t * (t + 1) / 2;
}

// interleaved right-looking chol + trinv of a 64x64 tile in LDS (256 threads)
// t, Xs: [64][S] arrays.  in: t = SPD tile.  out: t = L, Xs = inv(L)
template<typename T, int S>
__device__ inline void chol_inv_64t(T* t, T* Xs, T* diagL, int tid){
  for (int idx = tid; idx < 4096; idx += 256){
    int r = idx >> 6, c = idx & 63;
    Xs[r * S + c] = (r == c) ? (T)1 : (T)0;
  }
  __syncthreads();
  for (int j = 0; j < 64; ++j){
    T piv = tsqrt(tmax(t[j * S + j], (T)1e-30));
    T inv = (T)1 / piv;
    if (tid < 64){
      int r = j + 1 + tid;
      if (r < 64) t[r * S + j] *= inv;
      if (tid == 0) diagL[j] = piv;
    } else if (tid < 128){
      Xs[j * S + (tid - 64)] *= inv;
    }
    __syncthreads();
    int tg = tid >> 6, tr = tid & 63;
    for (int r2 = j + 1 + tg; r2 < 64; r2 += 4){
      T lj = t[r2 * S + j];
      int c = j + 1 + tr;
      if (c <= r2) t[r2 * S + c] -= lj * t[c * S + j];
      Xs[r2 * S + tr] = Xs[r2 * S + tr] - lj * Xs[j * S + tr];
    }
    __syncthreads();
  }
  if (tid < 64) t[tid * S + tid] = diagL[tid];
  __syncthreads();
}

// ---------------- setup kernels ----------------
__global__ __launch_bounds__(256) void k_prep(const float* X, const int* Y, float* x2, float* kappaf){
  int n = blockIdx.x * 256 + threadIdx.x;
  if (n >= NPTS) return;
  float s = 0.f;
  for (int d = 0; d < 64; ++d){ float v = X[n * 64 + d]; s += v * v; }
  x2[n] = s;
  kappaf[NPTS - 1 - n] = (float)Y[n] - 0.5f;
}

__global__ void k_computeK(const float* X, const float* x2, const float* osp, const float* lsp,
                           double* Ld){
  int j = blockIdx.x * 16 + threadIdx.x;
  int i = blockIdx.y * 16 + threadIdx.y;
  float os = osp[0], ls = lsp[0];
  float dot = 0.f;
  for (int d = 0; d < 64; ++d) dot += X[i * 64 + d] * X[j * 64 + d];
  float d2 = x2[i] + x2[j] - 2.0f * dot;
  d2 = fmaxf(d2, 0.0f);
  float kv = os * expf((-0.5f * d2) / (ls * ls));
  Ld[(size_t)i * NPTS + j] = (double)kv + (i == j ? 1e-6 : 0.0);
}

__global__ __launch_bounds__(256) void k_castL(const double* Ld, float* Lf){
  int idx = blockIdx.x * 256 + threadIdx.x;
  int i = idx >> 10, j = idx & 1023;
  Lf[idx] = (j <= i) ? (float)Ld[idx] : 0.0f;
}

__global__ __launch_bounds__(256) void k_logdetK(const double* Ld, float* ldetK){
  __shared__ double red[4];
  int tid = threadIdx.x;
  double s = 0.0;
  for (int i = tid; i < NPTS; i += 256) s += log(Ld[(size_t)i * NPTS + i]);
  for (int o = 32; o; o >>= 1) s += __shfl_down(s, o);
  if ((tid & 63) == 0) red[tid >> 6] = s;
  __syncthreads();
  if (tid == 0) ldetK[0] = (float)(2.0 * (red[0] + red[1] + red[2] + red[3]));
}

// ---------------- f64 dense blocked Cholesky (setup only) ----------------
__global__ __launch_bounds__(256) void k_chol_diag_inv_d(double* M, double* Dinv, int p){
  double* DI = Dinv + (size_t)p * 4096;
  int k0 = p * 64;
  __shared__ double t[64][65];
  __shared__ double Xs[64][65];
  __shared__ double diagL[64];
  int tid = threadIdx.x;
  for (int idx = tid; idx < 4096; idx += 256){
    int r = idx >> 6, c = idx & 63;
    t[r][c] = (c <= r) ? M[(size_t)(k0 + r) * NPTS + k0 + c] : 0.0;
  }
  __syncthreads();
  chol_inv_64t<double, 65>(&t[0][0], &Xs[0][0], &diagL[0], tid);
  for (int idx = tid; idx < 4096; idx += 256){
    int r = idx >> 6, c = idx & 63;
    M[(size_t)(k0 + r) * NPTS + k0 + c] = (c <= r) ? t[r][c] : 0.0;
    DI[idx] = Xs[r][c];
  }
}

__global__ __launch_bounds__(256) void k_chol_panel_d(double* M, const double* Dinv, int p){
  const double* DI = Dinv + (size_t)p * 4096;
  int r0 = (p + 1) * 64 + blockIdx.x * 64;
  __shared__ double Rs[64][65];
  __shared__ double Ds[64][65];
  int tid = threadIdx.x;
  for (int idx = tid; idx < 4096; idx += 256){
    int r = idx >> 6, c = idx & 63;
    Rs[r][c] = M[(size_t)(r0 + r) * NPTS + p * 64 + c];
    Ds[r][c] = DI[idx];
  }
  __syncthreads();
  int tx = tid & 15, ty = tid >> 4;
  double acc[4][4];
#pragma unroll
  for (int a = 0; a < 4; ++a)
#pragma unroll
    for (int b = 0; b < 4; ++b) acc[a][b] = 0.0;
  for (int k = 0; k < 64; ++k){
    double av[4], bv[4];
#pragma unroll
    for (int a = 0; a < 4; ++a) av[a] = Rs[ty * 4 + a][k];
#pragma unroll
    for (int b = 0; b < 4; ++b) bv[b] = Ds[tx * 4 + b][k];
#pragma unroll
    for (int a = 0; a < 4; ++a)
#pragma unroll
      for (int b = 0; b < 4; ++b) acc[a][b] += av[a] * bv[b];
  }
#pragma unroll
  for (int a = 0; a < 4; ++a)
#pragma unroll
    for (int b = 0; b < 4; ++b)
      M[(size_t)(r0 + ty * 4 + a) * NPTS + p * 64 + tx * 4 + b] = acc[a][b];
}

__global__ __launch_bounds__(256) void k_chol_update_d(double* M, int k0){
  __shared__ double Pa[64][65];
  __shared__ double Pb[64][65];
  int ti, tj; tri_decode(blockIdx.x, ti, tj);
  int bi = k0 + 64 + ti * 64;
  int bj = k0 + 64 + tj * 64;
  int tid = threadIdx.x;
  for (int idx = tid; idx < 4096; idx += 256){
    int r = idx >> 6, c = idx & 63;
    Pa[r][c] = M[(size_t)(bi + r) * NPTS + k0 + c];
    Pb[r][c] = M[(size_t)(bj + r) * NPTS + k0 + c];
  }
  __syncthreads();
  int tx = tid & 15, ty = tid >> 4;
  double acc[4][4];
#pragma unroll
  for (int a = 0; a < 4; ++a)
#pragma unroll
    for (int b = 0; b < 4; ++b) acc[a][b] = 0.0;
  for (int k = 0; k < 64; ++k){
    double av[4], bv[4];
#pragma unroll
    for (int a = 0; a < 4; ++a) av[a] = Pa[ty * 4 + a][k];
#pragma unroll
    for (int b = 0; b < 4; ++b) bv[b] = Pb[tx * 4 + b][k];
#pragma unroll
    for (int a = 0; a < 4; ++a)
#pragma unroll
      for (int b = 0; b < 4; ++b) acc[a][b] += av[a] * bv[b];
  }
#pragma unroll
  for (int a = 0; a < 4; ++a)
#pragma unroll
    for (int b = 0; b < 4; ++b){
      int gi = bi + ty * 4 + a, gj = bj + tx * 4 + b;
      M[(size_t)gi * NPTS + gj] -= acc[a][b];
    }
}

static void run_chol_d(double* A, double* Dinv, hipStream_t s){
  for (int p = 0; p < 16; ++p){
    k_chol_diag_inv_d<<<dim3(1), 256, 0, s>>>(A, Dinv, p);
    int nrb = 15 - p;
    if (nrb > 0){
      k_chol_panel_d<<<dim3(nrb), 256, 0, s>>>(A, Dinv, p);
      k_chol_update_d<<<dim3(nrb * (nrb + 1) / 2), 256, 0, s>>>(A, p * 64);
    }
  }
}

// ---------------- f64 triangular inverse (one-time, for Kinv), slice-parallel ----------------
__global__ __launch_bounds__(256) void k_trinv_copy_diag(const double* DinvD, double* Td){
  int p = blockIdx.x;
  for (int idx = threadIdx.x; idx < 4096; idx += 256){
    int r = idx >> 6, c = idx & 63;
    Td[(size_t)(p * 64 + r) * NPTS + p * 64 + c] = DinvD[(size_t)p * 4096 + idx];
  }
}

// partial product for level lev: block (J, s): G_s(I,J) = L(I,K) * X(K,J), K=J+s, I=J+lev
__global__ __launch_bounds__(256) void k_trinv_part(const double* Lm, const double* Td,
                                                    double* Gs, int lev){
  int J = blockIdx.x, s = blockIdx.y;
  int I = J + lev, K = J + s;
  __shared__ double Ta[64][65];
  __shared__ double Tb[64][65];
  int tid = threadIdx.x, tx = tid & 15, ty = tid >> 4;
  for (int idx = tid; idx < 4096; idx += 256){
    int r = idx >> 6, c = idx & 63;
    Ta[r][c] = Lm[(size_t)(I * 64 + r) * NPTS + K * 64 + c];
    Tb[r][c] = Td[(size_t)(K * 64 + r) * NPTS + J * 64 + c];
  }
  __syncthreads();
  double acc[4][4];
#pragma unroll
  for (int a = 0; a < 4; ++a)
#pragma unroll
    for (int b = 0; b < 4; ++b) acc[a][b] = 0.0;
  for (int k = 0; k < 64; ++k){
    double av[4], bv[4];
#pragma unroll
    for (int a = 0; a < 4; ++a) av[a] = Ta[ty * 4 + a][k];
#pragma unroll
    for (int b = 0; b < 4; ++b) bv[b] = Tb[k][tx * 4 + b];
#pragma unroll
    for (int a = 0; a < 4; ++a)
#pragma unroll
      for (int b = 0; b < 4; ++b) acc[a][b] += av[a] * bv[b];
  }
  double* out = Gs + ((size_t)J * 15 + s) * 4096;
#pragma unroll
  for (int a = 0; a < 4; ++a)
#pragma unroll
    for (int b = 0; b < 4; ++b)
      out[(ty * 4 + a) * 64 + tx * 4 + b] = acc[a][b];
}

// finish level lev: block J: X(I,J) = -DI(I) * sum_s G_s(I,J)
__global__ __launch_bounds__(256) void k_trinv_fin(double* Td, const double* Gs, int lev){
  int J = blockIdx.x, I = J + lev;
  __shared__ double Ta[64][65];
  __shared__ double Tb[64][65];
  int tid = threadIdx.x, tx = tid & 15, ty = tid >> 4;
  for (int idx = tid; idx < 4096; idx += 256){
    int r = idx >> 6, c = idx & 63;
    double g = 0.0;
    for (int s = 0; s < lev; ++s) g += Gs[((size_t)J * 15 + s) * 4096 + idx];
    Tb[r][c] = g;
    Ta[r][c] = Td[(size_t)(I * 64 + r) * NPTS + I * 64 + c];
  }
  __syncthreads();
  double ac2[4][4];
#pragma unroll
  for (int a = 0; a < 4; ++a)
#pragma unroll
    for (int b = 0; b < 4; ++b) ac2[a][b] = 0.0;
  for (int k = 0; k < 64; ++k){
    double av[4], bv[4];
#pragma unroll
    for (int a = 0; a < 4; ++a) av[a] = Ta[ty * 4 + a][k];
#pragma unroll
    for (int b = 0; b < 4; ++b) bv[b] = Tb[k][tx * 4 + b];
#pragma unroll
    for (int a = 0; a < 4; ++a)
#pragma unroll
      for (int b = 0; b < 4; ++b) ac2[a][b] += av[a] * bv[b];
  }
#pragma unroll
  for (int a = 0; a < 4; ++a)
#pragma unroll
    for (int b = 0; b < 4; ++b)
      Td[(size_t)(I * 64 + ty * 4 + a) * NPTS + J * 64 + tx * 4 + b] = -ac2[a][b];
}

// packed flipped Kinv: for block pair (ti<=tj), write tile (15-ti, 15-tj) of P*Kinv*P
__global__ __launch_bounds__(256) void k_syrk_kinv_flip(const double* Td, float* Kinvp){
  int a0, b0; tri_decode(blockIdx.x, a0, b0);   // a0 >= b0
  int ti = b0, tj = a0;                          // ti <= tj
  int kmin = tj;
  __shared__ double Ta[64][65];
  __shared__ double Tb[64][65];
  int tid = threadIdx.x, tx = tid & 15, ty = tid >> 4;
  double acc[4][4];
#pragma unroll
  for (int a = 0; a < 4; ++a)
#pragma unroll
    for (int b = 0; b < 4; ++b) acc[a][b] = 0.0;
  for (int K = kmin; K < 16; ++K){
    __syncthreads();
    for (int idx = tid; idx < 4096; idx += 256){
      int r = idx >> 6, c = idx & 63;
      Ta[r][c] = Td[(size_t)(K * 64 + r) * NPTS + ti * 64 + c];
      Tb[r][c] = Td[(size_t)(K * 64 + r) * NPTS + tj * 64 + c];
    }
    __syncthreads();
    for (int k = 0; k < 64; ++k){
      double av[4], bv[4];
#pragma unroll
      for (int a = 0; a < 4; ++a) av[a] = Ta[k][ty * 4 + a];
#pragma unroll
      for (int b = 0; b < 4; ++b) bv[b] = Tb[k][tx * 4 + b];
#pragma unroll
      for (int a = 0; a < 4; ++a)
#pragma unroll
        for (int b = 0; b < 4; ++b) acc[a][b] += av[a] * bv[b];
    }
  }
  int tileR = 15 - ti, tileC = 15 - tj;          // tileR >= tileC
  float* out = Kinvp + (size_t)(TRI(tileR) + tileC) * 4096;
#pragma unroll
  for (int a = 0; a < 4; ++a)
#pragma unroll
    for (int b = 0; b < 4; ++b){
      int rin = 63 - (ty * 4 + a), cin = 63 - (tx * 4 + b);
      out[rin * 64 + cin] = (float)acc[a][b];
    }
}

// ---------------- per-step kernels (packed f32) ----------------
__global__ __launch_bounds__(256) void k_buildA(const float* Kinvp, const float* omega, float* Ab,
                                                int c0, int clip){
  int d = c0 + blockIdx.y;
  float* A = Ab + (size_t)blockIdx.y * AST;
  int idx4 = blockIdx.x * 256 + threadIdx.x;     // 0..139263
  float4 v = ((const float4*)Kinvp)[idx4];
  int tile = idx4 >> 10;
  int ti, tj; tri_decode(tile, ti, tj);
  if (ti == tj){
    int e = (idx4 & 1023) * 4;
    int r = e >> 6, c = e & 63;
    if (c <= r && r < c + 4){
      float om = omega[(size_t)d * NPTS + (NPTS - 1 - (ti * 64 + r))];
      if (clip) om = fmaxf(om, 1e-16f);
      ((float*)&v)[r - c] += om;
    }
  }
  ((float4*)A)[idx4] = v;
}

// first diag tile chol+inv
__global__ __launch_bounds__(256) void k_diag0(float* Ab, float* Dinv){
  float* M = Ab + (size_t)blockIdx.x * AST;
  float* DI = Dinv + (size_t)blockIdx.x * 16 * 4096;
  __shared__ float t[64][65];
  __shared__ float Xs[64][65];
  __shared__ float diagL[64];
  int tid = threadIdx.x;
  for (int idx = tid; idx < 1024; idx += 256){
    float4 v = ((const float4*)M)[idx];
    int e = idx * 4, r = e >> 6, c = e & 63;
    t[r][c] = v.x; t[r][c + 1] = v.y; t[r][c + 2] = v.z; t[r][c + 3] = v.w;
  }
  __syncthreads();
  chol_inv_64t<float, 65>(&t[0][0], &Xs[0][0], &diagL[0], tid);
  for (int idx = tid; idx < 1024; idx += 256){
    int e = idx * 4, r = e >> 6, c = e & 63;
    float4 v, w;
    v.x = (c     <= r) ? t[r][c]     : 0.f;
    v.y = (c + 1 <= r) ? t[r][c + 1] : 0.f;
    v.z = (c + 2 <= r) ? t[r][c + 2] : 0.f;
    v.w = (c + 3 <= r) ? t[r][c + 3] : 0.f;
    w.x = Xs[r][c]; w.y = Xs[r][c + 1]; w.z = Xs[r][c + 2]; w.w = Xs[r][c + 3];
    ((float4*)M)[idx] = v;
    ((float4*)DI)[idx] = w;
  }
}

// panel: L(rt,p) = A(rt,p) * DI(p)^T   (transposed LDS, b128 reads, direct global write)
__global__ __launch_bounds__(256) void k_panel(float* Ab, const float* Dinv, int p){
  float* M = Ab + (size_t)blockIdx.y * AST;
  const float* DI = Dinv + ((size_t)blockIdx.y * 16 + p) * 4096;
  int rt = p + 1 + blockIdx.x;
  float* R = M + (size_t)(TRI(rt) + p) * 4096;
  __shared__ __align__(16) float Rst[64 * 68];
  __shared__ __align__(16) float Dst[64 * 68];
  int tid = threadIdx.x;
  for (int idx = tid; idx < 1024; idx += 256){
    float4 v = ((const float4*)R)[idx];
    float4 w = ((const float4*)DI)[idx];
    int e = idx * 4, r = e >> 6, c = e & 63;
    Rst[(c + 0) * 68 + r] = v.x; Rst[(c + 1) * 68 + r] = v.y;
    Rst[(c + 2) * 68 + r] = v.z; Rst[(c + 3) * 68 + r] = v.w;
    Dst[(c + 0) * 68 + r] = w.x; Dst[(c + 1) * 68 + r] = w.y;
    Dst[(c + 2) * 68 + r] = w.z; Dst[(c + 3) * 68 + r] = w.w;
  }
  __syncthreads();
  int tx = tid & 15, ty = tid >> 4;
  float acc[4][4];
#pragma unroll
  for (int a = 0; a < 4; ++a)
#pragma unroll
    for (int b = 0; b < 4; ++b) acc[a][b] = 0.f;
  for (int k = 0; k < 64; ++k){
    float4 av4 = *(const float4*)&Rst[k * 68 + ty * 4];
    float4 bv4 = *(const float4*)&Dst[k * 68 + tx * 4];
    float av[4] = {av4.x, av4.y, av4.z, av4.w};
    float bv[4] = {bv4.x, bv4.y, bv4.z, bv4.w};
#pragma unroll
    for (int a = 0; a < 4; ++a)
#pragma unroll
      for (int b = 0; b < 4; ++b) acc[a][b] += av[a] * bv[b];
  }
#pragma unroll
  for (int a = 0; a < 4; ++a){
    float4 v;
    v.x = acc[a][0]; v.y = acc[a][1]; v.z = acc[a][2]; v.w = acc[a][3];
    *((float4*)&R[(size_t)(ty * 4 + a) * 64 + tx * 4]) = v;
  }
}

// trailing update (transposed LDS, b128); block 0 also runs chol+inv of tile (p+1,p+1)
__global__ __launch_bounds__(256) void k_update_diag(float* Ab, float* Dinv, int p){
  float* M = Ab + (size_t)blockIdx.y * AST;
  __shared__ __align__(16) float Pat[64 * 68];
  __shared__ __align__(16) float Pbt[64 * 68];
  __shared__ float diagL[64];
  int t0, t1; tri_decode(blockIdx.x, t0, t1);    // t0 >= t1
  int bi = p + 1 + t0, bj = p + 1 + t1;
  const float* La = M + (size_t)(TRI(bi) + p) * 4096;
  const float* Lb = M + (size_t)(TRI(bj) + p) * 4096;
  float* Atile = M + (size_t)(TRI(bi) + bj) * 4096;
  int tid = threadIdx.x;
  for (int idx = tid; idx < 1024; idx += 256){
    float4 v = ((const float4*)La)[idx];
    float4 w = ((const float4*)Lb)[idx];
    int e = idx * 4, r = e >> 6, c = e & 63;
    Pat[(c + 0) * 68 + r] = v.x; Pat[(c + 1) * 68 + r] = v.y;
    Pat[(c + 2) * 68 + r] = v.z; Pat[(c + 3) * 68 + r] = v.w;
    Pbt[(c + 0) * 68 + r] = w.x; Pbt[(c + 1) * 68 + r] = w.y;
    Pbt[(c + 2) * 68 + r] = w.z; Pbt[(c + 3) * 68 + r] = w.w;
  }
  __syncthreads();
  int tx = tid & 15, ty = tid >> 4;
  float acc[4][4];
#pragma unroll
  for (int a = 0; a < 4; ++a)
#pragma unroll
    for (int b = 0; b < 4; ++b) acc[a][b] = 0.f;
  for (int k = 0; k < 64; ++k){
    float4 av4 = *(const float4*)&Pat[k * 68 + ty * 4];
    float4 bv4 = *(const float4*)&Pbt[k * 68 + tx * 4];
    float av[4] = {av4.x, av4.y, av4.z, av4.w};
    float bv[4] = {bv4.x, bv4.y, bv4.z, bv4.w};
#pragma unroll
    for (int a = 0; a < 4; ++a)
#pragma unroll
      for (int b = 0; b < 4; ++b) acc[a][b] += av[a] * bv[b];
  }
  if (blockIdx.x == 0){
    // tile (p+1,p+1): subtract in LDS (row-major), chol + inverse
    __syncthreads();
    for (int idx = tid; idx < 1024; idx += 256){
      float4 v = ((const float4*)Atile)[idx];
      int e = idx * 4, r = e >> 6, c = e & 63;
      Pat[r * 68 + c] = v.x; Pat[r * 68 + c + 1] = v.y;
      Pat[r * 68 + c + 2] = v.z; Pat[r * 68 + c + 3] = v.w;
    }
    __syncthreads();
#pragma unroll
    for (int a = 0; a < 4; ++a)
#pragma unroll
      for (int b = 0; b < 4; ++b)
        Pat[(ty * 4 + a) * 68 + tx * 4 + b] -= acc[a][b];
    __syncthreads();
    chol_inv_64t<float, 68>(Pat, Pbt, &diagL[0], tid);
    float* DI = Dinv + ((size_t)blockIdx.y * 16 + (p + 1)) * 4096;
    for (int idx = tid; idx < 1024; idx += 256){
      int e = idx * 4, r = e >> 6, c = e & 63;
      float4 v, w;
      v.x = (c     <= r) ? Pat[r * 68 + c]     : 0.f;
      v.y = (c + 1 <= r) ? Pat[r * 68 + c + 1] : 0.f;
      v.z = (c + 2 <= r) ? Pat[r * 68 + c + 2] : 0.f;
      v.w = (c + 3 <= r) ? Pat[r * 68 + c + 3] : 0.f;
      w.x = Pbt[r * 68 + c]; w.y = Pbt[r * 68 + c + 1];
      w.z = Pbt[r * 68 + c + 2]; w.w = Pbt[r * 68 + c + 3];
      ((float4*)Atile)[idx] = v;
      ((float4*)DI)[idx] = w;
    }
  } else {
    // direct global read-modify-write
#pragma unroll
    for (int a = 0; a < 4; ++a){
      float4 v = *((const float4*)&Atile[(size_t)(ty * 4 + a) * 64 + tx * 4]);
      v.x -= acc[a][0]; v.y -= acc[a][1]; v.z -= acc[a][2]; v.w -= acc[a][3];
      *((float4*)&Atile[(size_t)(ty * 4 + a) * 64 + tx * 4]) = v;
    }
  }
}

static void run_chol_f(float* A, float* Dinv, int batch, hipStream_t s){
  k_diag0<<<dim3(batch), 256, 0, s>>>(A, Dinv);
  for (int p = 0; p < 15; ++p){
    int nrb = 15 - p;
    k_panel<<<dim3(nrb, batch), 256, 0, s>>>(A, Dinv, p);
    k_update_diag<<<dim3(nrb * (nrb + 1) / 2, batch), 256, 0, s>>>(A, Dinv, p);
  }
}

// ---------------- fused per-step solves: z1 = Lb^-1 kappaf; f = P(Lb^-T z1 + Lb^-T P eps) ----
__global__ __launch_bounds__(256) void k_step_solve(const float* Ab, const float* DinvF,
                                                    const float* kappaf, const float* eps,
                                                    float* fbuf, int c0){
  int d0 = blockIdx.x, d = c0 + d0;
  const float* L = Ab + (size_t)d0 * AST;
  const float* DI = DinvF + (size_t)d0 * 16 * 4096;
  __shared__ float z1[NPTS], z2[NPTS];
  __shared__ float buf[2][64 * 65];
  __shared__ float p1[4][64], p2[4][64];
  int tid = threadIdx.x;
  float4 rg[4];
  auto loadDI = [&](int p){
#pragma unroll
    for (int j = 0; j < 4; ++j)
      rg[j] = *(const float4*)&DI[p * 4096 + j * 1024 + tid * 4];
  };
  auto loadL = [&](int row, int col){
    const float* T = L + (size_t)(TRI(row) + col) * 4096;
#pragma unroll
    for (int j = 0; j < 4; ++j)
      rg[j] = *(const float4*)&T[j * 1024 + tid * 4];
  };
  auto store = [&](int cur){
#pragma unroll
    for (int j = 0; j < 4; ++j){
      int e = j * 1024 + tid * 4; int r = e >> 6, c = e & 63;
      float* b = &buf[cur][r * 65 + c];
      b[0] = rg[j].x; b[1] = rg[j].y; b[2] = rg[j].z; b[3] = rg[j].w;
    }
  };
  for (int i = tid; i < NPTS; i += 256){
    z1[i] = kappaf[i];
    z2[NPTS - 1 - i] = eps[(size_t)d * NPTS + i];
  }
  // ---- forward: z1 <- Lb^-1 z1 ----
  loadDI(0);
  int cur = 0;
  for (int p = 0; p < 16; ++p){
    for (int rb = p; rb < 16; ++rb){
      store(cur);
      int np = p, nrb = rb + 1;
      if (nrb >= 16){ np = p + 1; nrb = np; }
      if (np < 16){ if (nrb == np) loadDI(np); else loadL(nrb, np); }
      __syncthreads();
      int rr = tid & 63, q = tid >> 6;
      float s = 0.f;
#pragma unroll
      for (int cc = 0; cc < 16; ++cc)
        s += buf[cur][rr * 65 + q * 16 + cc] * z1[p * 64 + q * 16 + cc];
      p1[q][rr] = s;
      __syncthreads();
      if (tid < 64){
        float v = p1[0][tid] + p1[1][tid] + p1[2][tid] + p1[3][tid];
        if (rb == p) z1[p * 64 + tid] = v;
        else z1[rb * 64 + tid] -= v;
      }
      __syncthreads();
      cur ^= 1;
    }
  }
  // ---- backward on z1 (mu path) and z2 (noise path) ----
  loadDI(15);
  for (int p = 15; p >= 0; --p){
    for (int cb = p; cb >= 0; --cb){
      store(cur);
      int np = p, ncb = cb - 1;
      if (ncb < 0){ np = p - 1; ncb = np; }
      if (np >= 0){ if (ncb == np) loadDI(np); else loadL(np, ncb); }
      __syncthreads();
      int cc = tid & 63, q = tid >> 6;
      float s1 = 0.f, s2 = 0.f;
#pragma unroll
      for (int rr = 0; rr < 16; ++rr){
        float t = buf[cur][(q * 16 + rr) * 65 + cc];
        s1 += t * z1[p * 64 + q * 16 + rr];
        s2 += t * z2[p * 64 + q * 16 + rr];
      }
      p1[q][cc] = s1; p2[q][cc] = s2;
      __syncthreads();
      if (tid < 64){
        float v1 = p1[0][tid] + p1[1][tid] + p1[2][tid] + p1[3][tid];
        float v2 = p2[0][tid] + p2[1][tid] + p2[2][tid] + p2[3][tid];
        if (cb == p){ z1[p * 64 + tid] = v1; z2[p * 64 + tid] = v2; }
        else { z1[cb * 64 + tid] -= v1; z2[cb * 64 + tid] -= v2; }
      }
      __syncthreads();
      cur ^= 1;
    }
  }
  for (int i = tid; i < NPTS; i += 256)
    fbuf[(size_t)d * NPTS + i] = z1[NPTS - 1 - i] + z2[NPTS - 1 - i];
}

// fused final (Woodbury): mll = 0.5*||Lb^-1 kappaf||^2 + sum log diag(DI) - 0.5*ldetK - N log2
__global__ __launch_bounds__(256) void k_final3(const float* Ab, const float* DinvF,
                                                const float* kappaf, const float* ldetK,
                                                float* mll, int c0){
  int d0 = blockIdx.x, d = c0 + d0;
  const float* L = Ab + (size_t)d0 * AST;
  const float* DI = DinvF + (size_t)d0 * 16 * 4096;
  __shared__ float z[NPTS];
  __shared__ float buf[2][64 * 65];
  __shared__ float part[4][64];
  __shared__ float redq[4];
  int tid = threadIdx.x;
  float4 rg[4];
  auto loadDI = [&](int p){
#pragma unroll
    for (int j = 0; j < 4; ++j)
      rg[j] = *(const float4*)&DI[p * 4096 + j * 1024 + tid * 4];
  };
  auto loadL = [&](int rbrow, int pcol){
    const float* T = L + (size_t)(TRI(rbrow) + pcol) * 4096;
#pragma unroll
    for (int j = 0; j < 4; ++j)
      rg[j] = *(const float4*)&T[j * 1024 + tid * 4];
  };
  auto store = [&](int cur){
#pragma unroll
    for (int j = 0; j < 4; ++j){
      int e = j * 1024 + tid * 4; int r = e >> 6, c = e & 63;
      float* b = &buf[cur][r * 65 + c];
      b[0] = rg[j].x; b[1] = rg[j].y; b[2] = rg[j].z; b[3] = rg[j].w;
    }
  };
  for (int i = tid; i < NPTS; i += 256) z[i] = kappaf[i];
  loadDI(0);
  int cur = 0;
  float ldacc = 0.f;
  for (int p = 0; p < 16; ++p){
    for (int rb = p; rb < 16; ++rb){
      store(cur);
      int np = p, nrb = rb + 1;
      if (nrb >= 16){ np = p + 1; nrb = np; }
      if (np < 16){ if (nrb == np) loadDI(np); else loadL(nrb, np); }
      __syncthreads();
      if (rb == p && tid < 64) ldacc += logf(buf[cur][tid * 65 + tid]);
      int rr = tid & 63, q = tid >> 6;
      float s = 0.f;
#pragma unroll
      for (int cc = 0; cc < 16; ++cc)
        s += buf[cur][rr * 65 + q * 16 + cc] * z[p * 64 + q * 16 + cc];
      part[q][rr] = s;
      __syncthreads();
      if (tid < 64){
        float v = part[0][tid] + part[1][tid] + part[2][tid] + part[3][tid];
        if (rb == p) z[p * 64 + tid] = v;
        else z[rb * 64 + tid] -= v;
      }
      __syncthreads();
      cur ^= 1;
    }
  }
  float q2 = 0.f;
  for (int i = tid; i < NPTS; i += 256) q2 += z[i] * z[i];
  int wid = tid >> 6, lane = tid & 63;
  for (int o = 32; o; o >>= 1) q2 += __shfl_down(q2, o);
  if (lane == 0) redq[wid] = q2;
  __syncthreads();
  if (tid < 64){
    float ldv = ldacc;
    for (int o = 32; o; o >>= 1) ldv += __shfl_down(ldv, o);
    if (tid == 0){
      float q2t = redq[0] + redq[1] + redq[2] + redq[3];
      mll[d] = 0.5f * q2t + ldv - 0.5f * ldetK[0] - 709.7827128933839f;
    }
  }
}

// ---------------- RNG kernels ----------------
__global__ __launch_bounds__(256) void k_gen_eps(u32 ka, u32 kb, float* eps){
  int i = blockIdx.x * 256 + threadIdx.x;
  if (i >= NDRAWS * NPTS) return;
  u32 bits = rand32(ka, kb, (u32)i, (u32)(NDRAWS * NPTS));
  eps[i] = normal_from_bits(bits);
}

__global__ __launch_bounds__(256) void k_init_f2(const float* Lf, const float* eps, float* f){
  int d = blockIdx.y, rb = blockIdx.x;
  __shared__ float tile[64][65];
  __shared__ float ev[64];
  __shared__ float part[4][64];
  int tid = threadIdx.x;
  int r = tid & 63, q = tid >> 6;
  float acc = 0.f;
  for (int kt = 0; kt <= rb; ++kt){
    __syncthreads();
#pragma unroll
    for (int j = 0; j < 4; ++j){
      int e = j * 1024 + tid * 4; int rr = e >> 6, cc = e & 63;
      float4 v = *(const float4*)&Lf[(size_t)(rb * 64 + rr) * NPTS + kt * 64 + cc];
      tile[rr][cc] = v.x; tile[rr][cc + 1] = v.y; tile[rr][cc + 2] = v.z; tile[rr][cc + 3] = v.w;
    }
    if (tid < 64) ev[tid] = eps[(size_t)d * NPTS + kt * 64 + tid];
    __syncthreads();
    int cmax = (kt == rb) ? (r + 1) : 64;
    for (int cc = q * 16; cc < q * 16 + 16; ++cc){
      if (cc < cmax) acc += tile[r][cc] * ev[cc];
    }
  }
  part[q][r] = acc;
  __syncthreads();
  if (tid < 64){
    float s = part[0][tid] + part[1][tid] + part[2][tid] + part[3][tid];
    f[(size_t)d * NPTS + rb * 64 + tid] = s;
  }
}

__global__ __launch_bounds__(256) void k_pg(u32 ka, u32 kb, const float* f, float* omega){
  int idx = blockIdx.x * 256 + threadIdx.x;
  if (idx >= NDRAWS * NPTS) return;
  float c = f[idx];
  float c2w = (c * c) / 39.47841760435743f;
  float sum = 0.f;
  u32 base = (u32)idx * NG;
  for (int g = 0; g < NG; ++g){
    u32 bits = rand32(ka, kb, base + (u32)g, (u32)(NDRAWS * NPTS * NG));
    float u = u01f(bits);
    float e = -log1pf(-u);
    float kk = (float)g + 0.5f;
    sum += e / (kk * kk + c2w);
  }
  omega[idx] = sum / 19.739208802178716f;
}

__global__ void k_out(const float* mll, float* out){
  if (threadIdx.x == 0){
    float s = 0.f;
    for (int dd = 0; dd < NDRAWS; ++dd) s += mll[dd];
    float m = s / (float)NDRAWS;
    out[0] = (-m) / (float)NPTS;
  }
}

// ---------------- host-side key derivation ----------------
static void host_split(u32 ka, u32 kb, int num, u32* outA, u32* outB){
#if PARTITIONABLE
  for (int j = 0; j < num; ++j) tf2x32(ka, kb, 0u, (u32)j, &outA[j], &outB[j]);
#else
  u32 flat[40];
  for (int k = 0; k < num; ++k){
    u32 a, b; tf2x32(ka, kb, (u32)k, (u32)(num + k), &a, &b);
    flat[k] = a; flat[num + k] = b;
  }
  for (int j = 0; j < num; ++j){ outA[j] = flat[2 * j]; outB[j] = flat[2 * j + 1]; }
#endif
}

extern "C" void kernel_launch(void* const* d_in, const int* in_sizes, int n_in,
                              void* d_out, int out_size, void* d_ws, size_t ws_size,
                              hipStream_t stream){
  const float* X  = (const float*)d_in[0];
  const int*   Y  = (const int*)d_in[1];
  const float* osp = (const float*)d_in[2];
  const float* lsp = (const float*)d_in[3];
  float* out = (float*)d_out;

  const size_t NN = (size_t)NPTS * NPTS;
  char* p = (char*)d_ws;
  // ---- persistent region (~2.5 MB) ----
  float* Kinvp  = (float*)p;  p += AST * 4;
  float* omega  = (float*)p;  p += (size_t)NDRAWS * NPTS * 4;
  float* fbuf   = (float*)p;  p += (size_t)NDRAWS * NPTS * 4;
  float* epsb   = (float*)p;  p += (size_t)NDRAWS * NPTS * 4;
  float* kappaf = (float*)p;  p += NPTS * 4;
  float* x2     = (float*)p;  p += NPTS * 4;
  float* mll    = (float*)p;  p += 128;
  float* ldetK  = (float*)p;  p += 128;
  uintptr_t ip = (uintptr_t)p; ip = (ip + 255) & ~(uintptr_t)255;
  char* cb = (char*)ip;

  // ---- setup-only aliases (used strictly before the Gibbs loop) ----
  double* Ld    = (double*)cb;                                        // 8 MB
  double* Td    = (double*)(cb + NN * 8);                             // 8 MB
  double* DinvD = (double*)(cb + NN * 16);                            // 512 KB
  float*  Lf    = (float*)(cb + NN * 16 + (size_t)16 * 4096 * 8);     // 4 MB
  double* Gslc  = (double*)(cb + NN * 16 + (size_t)16 * 4096 * 8 + NN * 4);  // 7.9 MB

  // ---- chunk buffers (overlay same region) ----
  size_t rem = ws_size - (size_t)(cb - (char*)d_ws);
  const size_t PER_DRAW = AST * 4 + (size_t)16 * 4096 * 4;
  int CH = (int)(rem / PER_DRAW);
  if (CH > NDRAWS) CH = NDRAWS;
  if (CH < 1) CH = 1;
  float* bufA  = (float*)cb;
  float* dinvF = (float*)(cb + (size_t)CH * AST * 4);

  // ---- keys ----
  u32 r3A[3], r3B[3];
  host_split(0u, 42u, 3, r3A, r3B);
  u32 kiA = r3A[0], kiB = r3B[0];
  u32 koA = r3A[1], koB = r3B[1];
  u32 klA = r3A[2], klB = r3B[2];
  u32 kkA[NSTEPS], kkB[NSTEPS];
  host_split(klA, klB, NSTEPS, kkA, kkB);
  u32 k1A[NSTEPS], k1B[NSTEPS], k2A[NSTEPS], k2B[NSTEPS];
  for (int t = 0; t < NSTEPS; ++t){
    u32 sA[2], sB[2];
    host_split(kkA[t], kkB[t], 2, sA, sB);
    k1A[t] = sA[0]; k1B[t] = sB[0];
    k2A[t] = sA[1]; k2B[t] = sB[1];
  }

  // ---- setup: K (f64), chol, Lf, logdet, slice-parallel trinv, packed flipped Kinv ----
  k_prep<<<dim3(4), 256, 0, stream>>>(X, Y, x2, kappaf);
  k_computeK<<<dim3(64, 64), dim3(16, 16), 0, stream>>>(X, x2, osp, lsp, Ld);
  run_chol_d(Ld, DinvD, stream);
  k_castL<<<dim3(4096), 256, 0, stream>>>(Ld, Lf);
  k_logdetK<<<dim3(1), 256, 0, stream>>>(Ld, ldetK);
  k_trinv_copy_diag<<<dim3(16), 256, 0, stream>>>(DinvD, Td);
  for (int lev = 1; lev < 16; ++lev){
    k_trinv_part<<<dim3(16 - lev, lev), 256, 0, stream>>>(Ld, Td, Gslc, lev);
    k_trinv_fin<<<dim3(16 - lev), 256, 0, stream>>>(Td, Gslc, lev);
  }
  k_syrk_kinv_flip<<<dim3(NTRI), 256, 0, stream>>>(Td, Kinvp);

  // ---- initial Gibbs state ----
  k_gen_eps<<<dim3(80), 256, 0, stream>>>(kiA, kiB, epsb);
  k_init_f2<<<dim3(16, NDRAWS), 256, 0, stream>>>(Lf, epsb, fbuf);
  k_pg<<<dim3(80), 256, 0, stream>>>(koA, koB, fbuf, omega);

  // ---- Gibbs steps ----
  for (int t = 0; t < NSTEPS; ++t){
    k_gen_eps<<<dim3(80), 256, 0, stream>>>(k1A[t], k1B[t], epsb);
    for (int c0 = 0; c0 < NDRAWS; c0 += CH){
      int nb = NDRAWS - c0 < CH ? NDRAWS - c0 : CH;
      k_buildA<<<dim3(544, nb), 256, 0, stream>>>(Kinvp, omega, bufA, c0, 0);
      run_chol_f(bufA, dinvF, nb, stream);
      k_step_solve<<<dim3(nb), 256, 0, stream>>>(bufA, dinvF, kappaf, epsb, fbuf, c0);
    }
    k_pg<<<dim3(80), 256, 0, stream>>>(k2A[t], k2B[t], fbuf, omega);
  }

  // ---- final mll (Woodbury) ----
  for (int c0 = 0; c0 < NDRAWS; c0 += CH){
    int nb = NDRAWS - c0 < CH ? NDRAWS - c0 : CH;
    k_buildA<<<dim3(544, nb), 256, 0, stream>>>(Kinvp, omega, bufA, c0, 1);
    run_chol_f(bufA, dinvF, nb, stream);
    k_final3<<<dim3(nb), 256, 0, stream>>>(bufA, dinvF, kappaf, ldetK, mll, c0);
  }
  k_out<<<dim3(1), 64, 0, stream>>>(mll, out);
}